// Round 17
// baseline (483.891 us; speedup 1.0000x reference)
//
#include <hip/hip_runtime.h>
#include <hip/hip_fp16.h>
#include <cstdint>

// ---------------------------------------------------------------------------
// GCN: 3x GCNConv(+ELU) + linear head.
// Norm factorized: norm = dinv[s]*w*dinv[d]. Gather tables store
// t[n] = dinv[n]*f[n] (fp16); agg computes out = dinv[d]*(t[d] + sum w*t[s]).
// perm = (src, w); build: hist -> scan -> LDS-tile scatter (512 thr, 1024
// bins) -> bucket_sort (128-node buckets, 512 thr, all-resident grid).
// Agg: plain-load perm stream + fp16 L2-resident tables + edge-split lanes.
// Round-17 change: 128-node buckets so bucket_sort's 782 blocks are all
// co-resident (was 391x16-wave blocks = 1.5 scheduling rounds), + 4-deep
// unroll in both sweeps.
// ---------------------------------------------------------------------------

typedef float __attribute__((ext_vector_type(4))) f4v;

__device__ inline float4 ldnt4(const float4* p) {
    f4v v = __builtin_nontemporal_load((const f4v*)p);
    float4 r;
    r.x = v.x; r.y = v.y; r.z = v.z; r.w = v.w;
    return r;
}

union H2I { __half2 h; int i; };
__device__ inline int h2i(__half2 h) { H2I u; u.h = h; return u.i; }

__device__ inline void acc8(float* a, int4 v, float n) {
    H2I u0, u1, u2, u3;
    u0.i = v.x; u1.i = v.y; u2.i = v.z; u3.i = v.w;
    float2 f0 = __half22float2(u0.h);
    float2 f1 = __half22float2(u1.h);
    float2 f2 = __half22float2(u2.h);
    float2 f3 = __half22float2(u3.h);
    a[0] = fmaf(n, f0.x, a[0]); a[1] = fmaf(n, f0.y, a[1]);
    a[2] = fmaf(n, f1.x, a[2]); a[3] = fmaf(n, f1.y, a[3]);
    a[4] = fmaf(n, f2.x, a[4]); a[5] = fmaf(n, f2.y, a[5]);
    a[6] = fmaf(n, f3.x, a[6]); a[7] = fmaf(n, f3.y, a[7]);
}

__device__ inline int4 pack8h(const float* a) {
    int4 r;
    r.x = h2i(__floats2half2_rn(a[0], a[1]));
    r.y = h2i(__floats2half2_rn(a[2], a[3]));
    r.z = h2i(__floats2half2_rn(a[4], a[5]));
    r.w = h2i(__floats2half2_rn(a[6], a[7]));
    return r;
}

// ---- Pass A: per-bucket edge counts. bucket = dst >> 7 (128 nodes).
__global__ void __launch_bounds__(256) bucket_hist(const int* __restrict__ dst,
                                                   int* __restrict__ bcnt,
                                                   int E, int nbuck, int chunk) {
    __shared__ int h[1024];
    for (int i = threadIdx.x; i < 1024; i += 256) h[i] = 0;
    __syncthreads();
    int c0 = blockIdx.x * chunk;
    int c1 = min(E, c0 + chunk);
    for (int i = c0 + threadIdx.x; i < c1; i += 256)
        atomicAdd(&h[((unsigned)dst[i]) >> 7], 1);
    __syncthreads();
    for (int i = threadIdx.x; i < nbuck; i += 256)
        if (h[i]) atomicAdd(&bcnt[i], h[i]);
}

// ---- scan of 1024 bucket counts (512 thr x 2 bins) -> boff, gcur.
__global__ void __launch_bounds__(512) bucket_scan(const int* __restrict__ bcnt,
                                                   int* __restrict__ boff,
                                                   int* __restrict__ gcur) {
    __shared__ int part[512];
    int t = threadIdx.x;
    int c0 = bcnt[2 * t], c1 = bcnt[2 * t + 1];
    int s = c0 + c1;
    part[t] = s;
    __syncthreads();
    for (int off = 1; off < 512; off <<= 1) {
        int v = part[t];
        int a = (t >= off) ? part[t - off] : 0;
        __syncthreads();
        part[t] = v + a;
        __syncthreads();
    }
    int excl = part[t] - s;
    boff[2 * t] = excl;          gcur[2 * t] = excl;
    boff[2 * t + 1] = excl + c0; gcur[2 * t + 1] = excl + c0;
    if (t == 511) boff[1024] = part[511];
}

// ---- Pass C: LDS counting-sort of 4096-edge tiles (512 thr, 1024 bins).
// pack: (local_dst(7b) << 24) | src(24b), payload = w
__global__ void __launch_bounds__(512) bucket_scatter(const int* __restrict__ src,
                                                      const int* __restrict__ dst,
                                                      const float* __restrict__ w,
                                                      int* __restrict__ gcur,
                                                      int2* __restrict__ bedge,
                                                      int E) {
    constexpr int TILE = 4096;
    __shared__ int hc[1024];    // histogram, then cursor (local offsets)
    __shared__ int gb[1024];
    __shared__ int part[512];
    __shared__ int2 sedge[TILE];
    __shared__ unsigned short sbuck[TILE];

    int t = threadIdx.x;
    int c0 = blockIdx.x * TILE;
    int mtile = min(TILE, E - c0);

    hc[t] = 0;
    hc[t + 512] = 0;
    __syncthreads();

    int  my_d[8];
    int  my_s[8];
    float my_w[8];
#pragma unroll
    for (int k = 0; k < 2; ++k) {
        int e0 = c0 + (t + k * 512) * 4;
        if (e0 + 4 <= E) {
            int4 d4 = *(const int4*)(dst + e0);
            int4 s4 = *(const int4*)(src + e0);
            float4 w4 = *(const float4*)(w + e0);
            my_d[k*4+0]=d4.x; my_d[k*4+1]=d4.y; my_d[k*4+2]=d4.z; my_d[k*4+3]=d4.w;
            my_s[k*4+0]=s4.x; my_s[k*4+1]=s4.y; my_s[k*4+2]=s4.z; my_s[k*4+3]=s4.w;
            my_w[k*4+0]=w4.x; my_w[k*4+1]=w4.y; my_w[k*4+2]=w4.z; my_w[k*4+3]=w4.w;
        } else {
#pragma unroll
            for (int j = 0; j < 4; ++j) {
                int e = e0 + j;
                bool ok = e < E;
                my_d[k*4+j] = ok ? dst[e] : -1;
                my_s[k*4+j] = ok ? src[e] : 0;
                my_w[k*4+j] = ok ? w[e] : 0.f;
            }
        }
    }
#pragma unroll
    for (int j = 0; j < 8; ++j)
        if (my_d[j] >= 0) atomicAdd(&hc[((unsigned)my_d[j]) >> 7], 1);
    __syncthreads();

    int h0 = hc[2 * t], h1 = hc[2 * t + 1];
    int s = h0 + h1;
    part[t] = s;
    __syncthreads();
    for (int off = 1; off < 512; off <<= 1) {
        int v = part[t];
        int a = (t >= off) ? part[t - off] : 0;
        __syncthreads();
        part[t] = v + a;
        __syncthreads();
    }
    int excl = part[t] - s;
    if (h0) gb[2 * t]     = atomicAdd(&gcur[2 * t],     h0) - excl;
    if (h1) gb[2 * t + 1] = atomicAdd(&gcur[2 * t + 1], h1) - (excl + h0);
    hc[2 * t] = excl;                       // cursors = local offsets
    hc[2 * t + 1] = excl + h0;
    __syncthreads();

#pragma unroll
    for (int j = 0; j < 8; ++j) {
        int d = my_d[j];
        if (d < 0) continue;
        unsigned ud = (unsigned)d;
        int b = ud >> 7;
        int p = atomicAdd(&hc[b], 1);
        sedge[p] = make_int2((int)(((ud & 127u) << 24) | (unsigned)my_s[j]),
                             __float_as_int(my_w[j]));
        sbuck[p] = (unsigned short)b;
    }
    __syncthreads();

    for (int i = t; i < mtile; i += 512) {
        int b = sbuck[i];
        bedge[gb[b] + i] = sedge[i];
    }
}

// ---- Pass D (fused, 512 thr, 128-node buckets, all-resident grid):
// deg -> row_ptr,dinv ; scatter -> perm=(src,w). 4-deep unrolled sweeps.
__global__ void __launch_bounds__(512) bucket_sort(const int* __restrict__ boff,
                                                   const int2* __restrict__ bedge,
                                                   int* __restrict__ row_ptr,
                                                   float* __restrict__ dinv,
                                                   int2* __restrict__ perm,
                                                   int N, int E) {
    __shared__ int cnt[128];
    __shared__ float deg[128];
    __shared__ int part[128];
    __shared__ int cur[128];
    int b = blockIdx.x;
    int base = boff[b];
    int m = boff[b + 1] - base;
    int t = threadIdx.x;
    if (t < 128) { cnt[t] = 0; deg[t] = 0.f; }
    __syncthreads();
    int i = t;
    for (; i + 1536 < m; i += 2048) {
        int2 e0 = bedge[base + i];
        int2 e1 = bedge[base + i + 512];
        int2 e2 = bedge[base + i + 1024];
        int2 e3 = bedge[base + i + 1536];
        atomicAdd(&cnt[((unsigned)e0.x) >> 24], 1);
        atomicAdd(&deg[((unsigned)e0.x) >> 24], __int_as_float(e0.y));
        atomicAdd(&cnt[((unsigned)e1.x) >> 24], 1);
        atomicAdd(&deg[((unsigned)e1.x) >> 24], __int_as_float(e1.y));
        atomicAdd(&cnt[((unsigned)e2.x) >> 24], 1);
        atomicAdd(&deg[((unsigned)e2.x) >> 24], __int_as_float(e2.y));
        atomicAdd(&cnt[((unsigned)e3.x) >> 24], 1);
        atomicAdd(&deg[((unsigned)e3.x) >> 24], __int_as_float(e3.y));
    }
    for (; i < m; i += 512) {
        int2 e = bedge[base + i];
        unsigned l = ((unsigned)e.x) >> 24;
        atomicAdd(&cnt[l], 1);
        atomicAdd(&deg[l], __int_as_float(e.y));
    }
    __syncthreads();
    if (t < 128) part[t] = cnt[t];
    __syncthreads();
    for (int off = 1; off < 128; off <<= 1) {
        int v = 0, a = 0;
        if (t < 128) { v = part[t]; a = (t >= off) ? part[t - off] : 0; }
        __syncthreads();
        if (t < 128) part[t] = v + a;
        __syncthreads();
    }
    if (t < 128) {
        int excl = part[t] - cnt[t];
        cur[t] = excl;
        int node = b * 128 + t;
        if (node < N) {
            row_ptr[node] = base + excl;
            dinv[node] = rsqrtf(deg[t] + 1.0f);
        }
    }
    if (b == 0 && t == 0) row_ptr[N] = E;
    __syncthreads();
    i = t;
    for (; i + 1536 < m; i += 2048) {
        int2 e0 = bedge[base + i];
        int2 e1 = bedge[base + i + 512];
        int2 e2 = bedge[base + i + 1024];
        int2 e3 = bedge[base + i + 1536];
        unsigned x0 = (unsigned)e0.x, x1 = (unsigned)e1.x;
        unsigned x2 = (unsigned)e2.x, x3 = (unsigned)e3.x;
        int p0 = base + atomicAdd(&cur[x0 >> 24], 1);
        int p1 = base + atomicAdd(&cur[x1 >> 24], 1);
        int p2 = base + atomicAdd(&cur[x2 >> 24], 1);
        int p3 = base + atomicAdd(&cur[x3 >> 24], 1);
        perm[p0] = make_int2((int)(x0 & 0xFFFFFFu), e0.y);
        perm[p1] = make_int2((int)(x1 & 0xFFFFFFu), e1.y);
        perm[p2] = make_int2((int)(x2 & 0xFFFFFFu), e2.y);
        perm[p3] = make_int2((int)(x3 & 0xFFFFFFu), e3.y);
    }
    for (; i < m; i += 512) {
        int2 e = bedge[base + i];
        unsigned ux = (unsigned)e.x;
        int pos = base + atomicAdd(&cur[ux >> 24], 1);
        perm[pos] = make_int2((int)(ux & 0xFFFFFFu), e.y);
    }
}

// x[N,256] @ W[256,16], prescaled by dinv[r] -> fp16 [N,16].
__global__ void __launch_bounds__(256) gemm_x16(const float* __restrict__ x,
                                                const float* __restrict__ W,
                                                const float* __restrict__ dinv,
                                                __half* __restrict__ xwh, int N) {
    __shared__ float Ws[256 * 16];
    for (int i = threadIdx.x; i < 256 * 16; i += 256) Ws[i] = W[i];
    __syncthreads();
    int c = threadIdx.x & 15;
    int rl = threadIdx.x >> 4;
    int r = blockIdx.x * 16 + rl;
    if (r >= N) return;
    const float4* x4 = (const float4*)(x + (size_t)r * 256);
    float acc = 0.f;
#pragma unroll 8
    for (int k4 = 0; k4 < 64; ++k4) {
        float4 v = ldnt4(x4 + k4);
        const float* wr = &Ws[k4 * 64 + c];
        acc += v.x * wr[0] + v.y * wr[16] + v.z * wr[32] + v.w * wr[48];
    }
    xwh[(size_t)r * 16 + c] = __float2half_rn(acc * dinv[r]);
}

// in[N,K] @ W[K,F] + bias -> out[N,F]. OUT_ELU: apply ELU.
// HALF_ROW: write fp16 row-major [N][F] prescaled by dinv[r]; else fp32.
template <int K, int F, bool OUT_ELU, bool HALF_ROW>
__global__ void __launch_bounds__(256) gemm_small(const float* __restrict__ in,
                                                  const float* __restrict__ W,
                                                  const float* __restrict__ bias,
                                                  const float* __restrict__ dinv,
                                                  void* __restrict__ outv, int N) {
    constexpr int ROWS = 256 / F;
    __shared__ float Ws[K * F];
    __shared__ float Is[ROWS * K];
    for (int i = threadIdx.x; i < K * F; i += 256) Ws[i] = W[i];
    int r0 = blockIdx.x * ROWS;
    for (int i = threadIdx.x; i < ROWS * K; i += 256)
        Is[i] = in[(size_t)r0 * K + i];
    __syncthreads();
    int c = threadIdx.x % F;
    int rl = threadIdx.x / F;
    int r = r0 + rl;
    float acc = bias[c];
#pragma unroll
    for (int k = 0; k < K; ++k) acc += Is[rl * K + k] * Ws[k * F + c];
    if (OUT_ELU) acc = acc > 0.f ? acc : expm1f(acc);
    if (HALF_ROW) {
        ((__half*)outv)[(size_t)r * F + c] = __float2half_rn(acc * dinv[r]);
    } else {
        ((float*)outv)[(size_t)r * F + c] = acc;
    }
}

// ---- fp16 prescaled-table gather-aggregate with edge-split lanes.
// Table: t[n] = dinv[n]*f[n], fp16 row-major [N][8*FH] (int4 = node*FH + q).
// Lanes/node = FH*2: q = feature chunk, e = edge half; shfl_xor(FH) merges.
// Math: sum = t[node] + sum_e w_e * t[src_e]; out = dinv[node]*sum [+b, ELU].
template <int FH, bool HALF_OUT>
__global__ void __launch_bounds__(256) agg_es(const int* __restrict__ row_ptr,
                                              const int2* __restrict__ perm,
                                              const int4* __restrict__ tab,
                                              const float* __restrict__ dinv,
                                              const float* __restrict__ bias,
                                              void* __restrict__ outv, int N) {
    constexpr int LPN = FH * 2;
    constexpr int NPB = 256 / LPN;
    int node = blockIdx.x * NPB + threadIdx.x / LPN;
    int sub = threadIdx.x % LPN;
    int q = sub % FH;
    int e = sub / FH;
    if (node >= N) return;
    float a0[8], a1[8], a2[8], a3[8];
#pragma unroll
    for (int i = 0; i < 8; ++i) { a0[i] = 0.f; a1[i] = 0.f; a2[i] = 0.f; a3[i] = 0.f; }
    if (e == 0) acc8(a0, tab[(size_t)node * FH + q], 1.0f);   // self-loop (w=1)
    int beg = row_ptr[node];
    int end = row_ptr[node + 1];
    int half = (end - beg) >> 1;
    int j = beg + e * half;
    int je = e ? end : (beg + half);
    for (; j + 7 < je; j += 8) {
        int2 p0 = perm[j];
        int2 p1 = perm[j + 1];
        int2 p2 = perm[j + 2];
        int2 p3 = perm[j + 3];
        int2 p4 = perm[j + 4];
        int2 p5 = perm[j + 5];
        int2 p6 = perm[j + 6];
        int2 p7 = perm[j + 7];
        int4 v0 = tab[(size_t)p0.x * FH + q];
        int4 v1 = tab[(size_t)p1.x * FH + q];
        int4 v2 = tab[(size_t)p2.x * FH + q];
        int4 v3 = tab[(size_t)p3.x * FH + q];
        int4 v4 = tab[(size_t)p4.x * FH + q];
        int4 v5 = tab[(size_t)p5.x * FH + q];
        int4 v6 = tab[(size_t)p6.x * FH + q];
        int4 v7 = tab[(size_t)p7.x * FH + q];
        acc8(a0, v0, __int_as_float(p0.y));
        acc8(a1, v1, __int_as_float(p1.y));
        acc8(a2, v2, __int_as_float(p2.y));
        acc8(a3, v3, __int_as_float(p3.y));
        acc8(a0, v4, __int_as_float(p4.y));
        acc8(a1, v5, __int_as_float(p5.y));
        acc8(a2, v6, __int_as_float(p6.y));
        acc8(a3, v7, __int_as_float(p7.y));
    }
    for (; j + 3 < je; j += 4) {
        int2 p0 = perm[j];
        int2 p1 = perm[j + 1];
        int2 p2 = perm[j + 2];
        int2 p3 = perm[j + 3];
        int4 v0 = tab[(size_t)p0.x * FH + q];
        int4 v1 = tab[(size_t)p1.x * FH + q];
        int4 v2 = tab[(size_t)p2.x * FH + q];
        int4 v3 = tab[(size_t)p3.x * FH + q];
        acc8(a0, v0, __int_as_float(p0.y));
        acc8(a1, v1, __int_as_float(p1.y));
        acc8(a2, v2, __int_as_float(p2.y));
        acc8(a3, v3, __int_as_float(p3.y));
    }
    for (; j < je; ++j) {
        int2 p0 = perm[j];
        acc8(a0, tab[(size_t)p0.x * FH + q], __int_as_float(p0.y));
    }
    float r[8];
#pragma unroll
    for (int i = 0; i < 8; ++i) {
        r[i] = (a0[i] + a1[i]) + (a2[i] + a3[i]);
        r[i] += __shfl_xor(r[i], FH);     // merge edge halves
    }
    if (e) return;
    float dv = dinv[node];
    if (HALF_OUT) {
#pragma unroll
        for (int i = 0; i < 8; ++i) {
            float v = r[i] * dv + bias[q * 8 + i];
            v = v > 0.f ? v : expm1f(v);
            r[i] = v * dv;                 // prescale next table
        }
        ((int4*)outv)[(size_t)node * FH + q] = pack8h(r);
    } else {
        float4* o4 = (float4*)outv;
        float4 lo = {r[0] * dv, r[1] * dv, r[2] * dv, r[3] * dv};
        float4 hi = {r[4] * dv, r[5] * dv, r[6] * dv, r[7] * dv};
        size_t base = ((size_t)node * FH + q) * 2;
        o4[base] = lo;
        o4[base + 1] = hi;
    }
}

extern "C" void kernel_launch(void* const* d_in, const int* in_sizes, int n_in,
                              void* d_out, int out_size, void* d_ws, size_t ws_size,
                              hipStream_t stream) {
    const float* x  = (const float*)d_in[0];
    const int*   ei = (const int*)d_in[1];
    const float* w  = (const float*)d_in[2];
    const float* W0 = (const float*)d_in[3];
    const float* b0 = (const float*)d_in[4];
    const float* W1 = (const float*)d_in[5];
    const float* b1 = (const float*)d_in[6];
    const float* W2 = (const float*)d_in[7];
    const float* b2 = (const float*)d_in[8];
    const float* Wm = (const float*)d_in[9];
    const float* bm = (const float*)d_in[10];
    float* out = (float*)d_out;

    const int N = in_sizes[0] / 256;
    const int E = in_sizes[2];
    const int* src = ei;
    const int* dst = ei + E;
    const int nbuck = (N + 127) >> 7;      // 128-node buckets (<=1024)

    char* ws = (char*)d_ws;
    size_t off = 0;
    auto alloc = [&](size_t bytes) {
        void* p = ws + off;
        off = (off + bytes + 255) & ~(size_t)255;
        return p;
    };
    float* dinv    = (float*)alloc((size_t)N * 4);
    int*   row_ptr = (int*)alloc(((size_t)N + 1) * 4);
    int*   bcnt    = (int*)alloc(1032 * 4);
    int*   boff    = (int*)alloc(1032 * 4);
    int*   gcur    = (int*)alloc(1032 * 4);
    // bedge region (E*8 bytes), aliased by feature buffers after CSR build:
    char*  regE    = (char*)alloc((size_t)E * 8);
    int2*  perm    = (int2*)alloc((size_t)E * 8);

    int2*  bedge = (int2*)regE;
    size_t eo = 0;
    auto sub = [&](size_t bytes) {
        char* p = regE + eo;
        eo = (eo + bytes + 255) & ~(size_t)255;
        return p;
    };
    __half* T0_h  = (__half*)sub((size_t)N * 16 * 2);   // 3.2MB  dinv*xw
    __half* T1_h  = (__half*)sub((size_t)N * 16 * 2);   // 3.2MB  dinv*h1
    __half* T2_h  = (__half*)sub((size_t)N * 32 * 2);   // 6.4MB  dinv*h2 [N][32]
    float*  AG1_f = (float*)sub((size_t)N * 16 * 4);    // 6.4MB
    float*  AG2_f = (float*)sub((size_t)N * 32 * 4);    // 12.8MB
    float*  H3_f  = (float*)sub((size_t)N * 32 * 4);    // 12.8MB (total ~44.8MB <= E*8)

    hipMemsetAsync(bcnt, 0, 1024 * 4, stream);

    const int CH = 8192;
    const int sblk = (E + CH - 1) / CH;

    // ---- build CSR (layer-invariant): perm = (src, w)
    bucket_hist<<<sblk, 256, 0, stream>>>(dst, bcnt, E, nbuck, CH);
    bucket_scan<<<1, 512, 0, stream>>>(bcnt, boff, gcur);
    bucket_scatter<<<(E + 4095) / 4096, 512, 0, stream>>>(src, dst, w, gcur, bedge, E);
    bucket_sort<<<nbuck, 512, 0, stream>>>(boff, bedge, row_ptr, dinv, perm, N, E);
    // bedge dead from here; regE reused for feature buffers.

    const int AGB2 = (N + 63) / 64;     // FH=2: 4 lanes/node
    const int AGB4 = (N + 31) / 32;     // FH=4: 8 lanes/node

    // ---- layer 0: T0 = dinv*(x@W0) fp16 ; T1 = dinv*elu(dinv*sum + b0) fp16
    gemm_x16<<<(N + 15) / 16, 256, 0, stream>>>(x, W0, dinv, T0_h, N);
    agg_es<2, true><<<AGB2, 256, 0, stream>>>(row_ptr, perm, (const int4*)T0_h, dinv, b0, T1_h, N);

    // ---- layer 1: AG1 = dinv*sum(T1) fp32 ; T2 = dinv*elu(AG1@W1+b1) fp16
    agg_es<2, false><<<AGB2, 256, 0, stream>>>(row_ptr, perm, (const int4*)T1_h, dinv, nullptr, AG1_f, N);
    gemm_small<16, 32, true, true><<<(N + 7) / 8, 256, 0, stream>>>(AG1_f, W1, b1, dinv, T2_h, N);

    // ---- layer 2: AG2 = dinv*sum(T2) fp32 ; H3 = elu(AG2@W2+b2) fp32
    agg_es<4, false><<<(N + 31) / 32, 256, 0, stream>>>(row_ptr, perm, (const int4*)T2_h, dinv, nullptr, AG2_f, N);
    gemm_small<32, 32, true, false><<<(N + 7) / 8, 256, 0, stream>>>(AG2_f, W2, b2, nullptr, H3_f, N);

    // ---- head: out = H3@Wm + bm
    gemm_small<32, 16, false, false><<<(N + 15) / 16, 256, 0, stream>>>(H3_f, Wm, bm, nullptr, out, N);
}

// Round 18
// 461.722 us; speedup vs baseline: 1.0480x; 1.0480x over previous
//
#include <hip/hip_runtime.h>
#include <hip/hip_fp16.h>
#include <cstdint>

// ---------------------------------------------------------------------------
// GCN: 3x GCNConv(+ELU) + linear head.
// Norm factorized: norm = dinv[s]*w*dinv[d]. Gather tables store
// t[n] = dinv[n]*f[n] (fp16); agg computes out = dinv[d]*(t[d] + sum w*t[s]).
// perm = (src, w); build: hist -> scan -> LDS-tile scatter (512 thr, 512
// bins, 256-node buckets) -> bucket_sort (1024 thr, 4-deep unrolled sweeps).
// Agg: plain-load perm stream + fp16 L2-resident tables + edge-split lanes.
// Round-18: round-16 build geometry (best: 467us) + unroll in bucket_sort
// (round-17's 1024-bin scatter cost more than its sort gain; reverted).
// ---------------------------------------------------------------------------

typedef float __attribute__((ext_vector_type(4))) f4v;

__device__ inline float4 ldnt4(const float4* p) {
    f4v v = __builtin_nontemporal_load((const f4v*)p);
    float4 r;
    r.x = v.x; r.y = v.y; r.z = v.z; r.w = v.w;
    return r;
}

union H2I { __half2 h; int i; };
__device__ inline int h2i(__half2 h) { H2I u; u.h = h; return u.i; }

__device__ inline void acc8(float* a, int4 v, float n) {
    H2I u0, u1, u2, u3;
    u0.i = v.x; u1.i = v.y; u2.i = v.z; u3.i = v.w;
    float2 f0 = __half22float2(u0.h);
    float2 f1 = __half22float2(u1.h);
    float2 f2 = __half22float2(u2.h);
    float2 f3 = __half22float2(u3.h);
    a[0] = fmaf(n, f0.x, a[0]); a[1] = fmaf(n, f0.y, a[1]);
    a[2] = fmaf(n, f1.x, a[2]); a[3] = fmaf(n, f1.y, a[3]);
    a[4] = fmaf(n, f2.x, a[4]); a[5] = fmaf(n, f2.y, a[5]);
    a[6] = fmaf(n, f3.x, a[6]); a[7] = fmaf(n, f3.y, a[7]);
}

__device__ inline int4 pack8h(const float* a) {
    int4 r;
    r.x = h2i(__floats2half2_rn(a[0], a[1]));
    r.y = h2i(__floats2half2_rn(a[2], a[3]));
    r.z = h2i(__floats2half2_rn(a[4], a[5]));
    r.w = h2i(__floats2half2_rn(a[6], a[7]));
    return r;
}

// ---- Pass A: per-bucket edge counts. bucket = dst >> 8.
__global__ void __launch_bounds__(256) bucket_hist(const int* __restrict__ dst,
                                                   int* __restrict__ bcnt,
                                                   int E, int nbuck, int chunk) {
    __shared__ int h[512];
    for (int i = threadIdx.x; i < 512; i += 256) h[i] = 0;
    __syncthreads();
    int c0 = blockIdx.x * chunk;
    int c1 = min(E, c0 + chunk);
    for (int i = c0 + threadIdx.x; i < c1; i += 256)
        atomicAdd(&h[((unsigned)dst[i]) >> 8], 1);
    __syncthreads();
    for (int i = threadIdx.x; i < nbuck; i += 256)
        if (h[i]) atomicAdd(&bcnt[i], h[i]);
}

// ---- scan of bucket counts -> boff[nbuck+1], global cursors.
__global__ void __launch_bounds__(512) bucket_scan(const int* __restrict__ bcnt,
                                                   int* __restrict__ boff,
                                                   int* __restrict__ gcur,
                                                   int nbuck) {
    __shared__ int part[512];
    int t = threadIdx.x;
    part[t] = (t < nbuck) ? bcnt[t] : 0;
    __syncthreads();
    for (int off = 1; off < 512; off <<= 1) {
        int v = part[t];
        int a = (t >= off) ? part[t - off] : 0;
        __syncthreads();
        part[t] = v + a;
        __syncthreads();
    }
    if (t < nbuck) {
        int excl = (t > 0) ? part[t - 1] : 0;
        boff[t] = excl;
        gcur[t] = excl;
        if (t == nbuck - 1) boff[nbuck] = part[t];  // == E
    }
}

// ---- Pass C: LDS counting-sort of 4096-edge tiles (512 thr, 8 edges/thr).
// pack: (local_dst(8b) << 24) | src(24b), payload = w
__global__ void __launch_bounds__(512) bucket_scatter(const int* __restrict__ src,
                                                      const int* __restrict__ dst,
                                                      const float* __restrict__ w,
                                                      int* __restrict__ gcur,
                                                      int2* __restrict__ bedge,
                                                      int E) {
    constexpr int TILE = 4096;
    __shared__ int hc[512];     // histogram, then cursor (local offsets)
    __shared__ int gb[512];
    __shared__ int part[512];
    __shared__ int2 sedge[TILE];
    __shared__ unsigned short sbuck[TILE];

    int t = threadIdx.x;
    int c0 = blockIdx.x * TILE;
    int mtile = min(TILE, E - c0);

    hc[t] = 0;
    __syncthreads();

    int  my_d[8];
    int  my_s[8];
    float my_w[8];
#pragma unroll
    for (int k = 0; k < 2; ++k) {
        int e0 = c0 + (t + k * 512) * 4;
        if (e0 + 4 <= E) {
            int4 d4 = *(const int4*)(dst + e0);
            int4 s4 = *(const int4*)(src + e0);
            float4 w4 = *(const float4*)(w + e0);
            my_d[k*4+0]=d4.x; my_d[k*4+1]=d4.y; my_d[k*4+2]=d4.z; my_d[k*4+3]=d4.w;
            my_s[k*4+0]=s4.x; my_s[k*4+1]=s4.y; my_s[k*4+2]=s4.z; my_s[k*4+3]=s4.w;
            my_w[k*4+0]=w4.x; my_w[k*4+1]=w4.y; my_w[k*4+2]=w4.z; my_w[k*4+3]=w4.w;
        } else {
#pragma unroll
            for (int j = 0; j < 4; ++j) {
                int e = e0 + j;
                bool ok = e < E;
                my_d[k*4+j] = ok ? dst[e] : -1;
                my_s[k*4+j] = ok ? src[e] : 0;
                my_w[k*4+j] = ok ? w[e] : 0.f;
            }
        }
    }
#pragma unroll
    for (int j = 0; j < 8; ++j)
        if (my_d[j] >= 0) atomicAdd(&hc[((unsigned)my_d[j]) >> 8], 1);
    __syncthreads();

    int hb = hc[t];
    part[t] = hb;
    __syncthreads();
    for (int off = 1; off < 512; off <<= 1) {
        int v = part[t];
        int a = (t >= off) ? part[t - off] : 0;
        __syncthreads();
        part[t] = v + a;
        __syncthreads();
    }
    int excl = part[t] - hb;
    hc[t] = excl;                                   // cursor = local offset
    gb[t] = hb ? (atomicAdd(&gcur[t], hb) - excl) : 0;
    __syncthreads();

#pragma unroll
    for (int j = 0; j < 8; ++j) {
        int d = my_d[j];
        if (d < 0) continue;
        unsigned ud = (unsigned)d;
        int b = ud >> 8;
        int p = atomicAdd(&hc[b], 1);
        sedge[p] = make_int2((int)(((ud & 255u) << 24) | (unsigned)my_s[j]),
                             __float_as_int(my_w[j]));
        sbuck[p] = (unsigned short)b;
    }
    __syncthreads();

    for (int i = t; i < mtile; i += 512) {
        int b = sbuck[i];
        bedge[gb[b] + i] = sedge[i];
    }
}

// ---- Pass D (fused, 1024 thr, 4-deep unrolled sweeps): deg -> row_ptr,dinv;
// scatter -> perm=(src,w). Second sweep re-reads the L2-hot bucket run.
__global__ void __launch_bounds__(1024) bucket_sort(const int* __restrict__ boff,
                                                    const int2* __restrict__ bedge,
                                                    int* __restrict__ row_ptr,
                                                    float* __restrict__ dinv,
                                                    int2* __restrict__ perm,
                                                    int N, int E) {
    __shared__ int cnt[256];
    __shared__ float deg[256];
    __shared__ int part[256];
    __shared__ int cur[256];
    int b = blockIdx.x;
    int base = boff[b];
    int m = boff[b + 1] - base;
    int t = threadIdx.x;
    if (t < 256) { cnt[t] = 0; deg[t] = 0.f; }
    __syncthreads();
    int i = t;
    for (; i + 3072 < m; i += 4096) {
        int2 e0 = bedge[base + i];
        int2 e1 = bedge[base + i + 1024];
        int2 e2 = bedge[base + i + 2048];
        int2 e3 = bedge[base + i + 3072];
        atomicAdd(&cnt[((unsigned)e0.x) >> 24], 1);
        atomicAdd(&deg[((unsigned)e0.x) >> 24], __int_as_float(e0.y));
        atomicAdd(&cnt[((unsigned)e1.x) >> 24], 1);
        atomicAdd(&deg[((unsigned)e1.x) >> 24], __int_as_float(e1.y));
        atomicAdd(&cnt[((unsigned)e2.x) >> 24], 1);
        atomicAdd(&deg[((unsigned)e2.x) >> 24], __int_as_float(e2.y));
        atomicAdd(&cnt[((unsigned)e3.x) >> 24], 1);
        atomicAdd(&deg[((unsigned)e3.x) >> 24], __int_as_float(e3.y));
    }
    for (; i < m; i += 1024) {
        int2 e = bedge[base + i];
        unsigned l = ((unsigned)e.x) >> 24;
        atomicAdd(&cnt[l], 1);
        atomicAdd(&deg[l], __int_as_float(e.y));
    }
    __syncthreads();
    if (t < 256) part[t] = cnt[t];
    __syncthreads();
    for (int off = 1; off < 256; off <<= 1) {
        int v = 0, a = 0;
        if (t < 256) { v = part[t]; a = (t >= off) ? part[t - off] : 0; }
        __syncthreads();
        if (t < 256) part[t] = v + a;
        __syncthreads();
    }
    if (t < 256) {
        int excl = part[t] - cnt[t];
        cur[t] = excl;
        int node = b * 256 + t;
        if (node < N) {
            row_ptr[node] = base + excl;
            dinv[node] = rsqrtf(deg[t] + 1.0f);
        }
    }
    if (b == 0 && t == 0) row_ptr[N] = E;
    __syncthreads();
    i = t;
    for (; i + 3072 < m; i += 4096) {
        int2 e0 = bedge[base + i];
        int2 e1 = bedge[base + i + 1024];
        int2 e2 = bedge[base + i + 2048];
        int2 e3 = bedge[base + i + 3072];
        unsigned x0 = (unsigned)e0.x, x1 = (unsigned)e1.x;
        unsigned x2 = (unsigned)e2.x, x3 = (unsigned)e3.x;
        int p0 = base + atomicAdd(&cur[x0 >> 24], 1);
        int p1 = base + atomicAdd(&cur[x1 >> 24], 1);
        int p2 = base + atomicAdd(&cur[x2 >> 24], 1);
        int p3 = base + atomicAdd(&cur[x3 >> 24], 1);
        perm[p0] = make_int2((int)(x0 & 0xFFFFFFu), e0.y);
        perm[p1] = make_int2((int)(x1 & 0xFFFFFFu), e1.y);
        perm[p2] = make_int2((int)(x2 & 0xFFFFFFu), e2.y);
        perm[p3] = make_int2((int)(x3 & 0xFFFFFFu), e3.y);
    }
    for (; i < m; i += 1024) {
        int2 e = bedge[base + i];
        unsigned ux = (unsigned)e.x;
        int pos = base + atomicAdd(&cur[ux >> 24], 1);
        perm[pos] = make_int2((int)(ux & 0xFFFFFFu), e.y);
    }
}

// x[N,256] @ W[256,16], prescaled by dinv[r] -> fp16 [N,16].
__global__ void __launch_bounds__(256) gemm_x16(const float* __restrict__ x,
                                                const float* __restrict__ W,
                                                const float* __restrict__ dinv,
                                                __half* __restrict__ xwh, int N) {
    __shared__ float Ws[256 * 16];
    for (int i = threadIdx.x; i < 256 * 16; i += 256) Ws[i] = W[i];
    __syncthreads();
    int c = threadIdx.x & 15;
    int rl = threadIdx.x >> 4;
    int r = blockIdx.x * 16 + rl;
    if (r >= N) return;
    const float4* x4 = (const float4*)(x + (size_t)r * 256);
    float acc = 0.f;
#pragma unroll 8
    for (int k4 = 0; k4 < 64; ++k4) {
        float4 v = ldnt4(x4 + k4);
        const float* wr = &Ws[k4 * 64 + c];
        acc += v.x * wr[0] + v.y * wr[16] + v.z * wr[32] + v.w * wr[48];
    }
    xwh[(size_t)r * 16 + c] = __float2half_rn(acc * dinv[r]);
}

// in[N,K] @ W[K,F] + bias -> out[N,F]. OUT_ELU: apply ELU.
// HALF_ROW: write fp16 row-major [N][F] prescaled by dinv[r]; else fp32.
template <int K, int F, bool OUT_ELU, bool HALF_ROW>
__global__ void __launch_bounds__(256) gemm_small(const float* __restrict__ in,
                                                  const float* __restrict__ W,
                                                  const float* __restrict__ bias,
                                                  const float* __restrict__ dinv,
                                                  void* __restrict__ outv, int N) {
    constexpr int ROWS = 256 / F;
    __shared__ float Ws[K * F];
    __shared__ float Is[ROWS * K];
    for (int i = threadIdx.x; i < K * F; i += 256) Ws[i] = W[i];
    int r0 = blockIdx.x * ROWS;
    for (int i = threadIdx.x; i < ROWS * K; i += 256)
        Is[i] = in[(size_t)r0 * K + i];
    __syncthreads();
    int c = threadIdx.x % F;
    int rl = threadIdx.x / F;
    int r = r0 + rl;
    float acc = bias[c];
#pragma unroll
    for (int k = 0; k < K; ++k) acc += Is[rl * K + k] * Ws[k * F + c];
    if (OUT_ELU) acc = acc > 0.f ? acc : expm1f(acc);
    if (HALF_ROW) {
        ((__half*)outv)[(size_t)r * F + c] = __float2half_rn(acc * dinv[r]);
    } else {
        ((float*)outv)[(size_t)r * F + c] = acc;
    }
}

// ---- fp16 prescaled-table gather-aggregate with edge-split lanes.
// Table: t[n] = dinv[n]*f[n], fp16 row-major [N][8*FH] (int4 = node*FH + q).
// Lanes/node = FH*2: q = feature chunk, e = edge half; shfl_xor(FH) merges.
// Math: sum = t[node] + sum_e w_e * t[src_e]; out = dinv[node]*sum [+b, ELU].
template <int FH, bool HALF_OUT>
__global__ void __launch_bounds__(256) agg_es(const int* __restrict__ row_ptr,
                                              const int2* __restrict__ perm,
                                              const int4* __restrict__ tab,
                                              const float* __restrict__ dinv,
                                              const float* __restrict__ bias,
                                              void* __restrict__ outv, int N) {
    constexpr int LPN = FH * 2;
    constexpr int NPB = 256 / LPN;
    int node = blockIdx.x * NPB + threadIdx.x / LPN;
    int sub = threadIdx.x % LPN;
    int q = sub % FH;
    int e = sub / FH;
    if (node >= N) return;
    float a0[8], a1[8], a2[8], a3[8];
#pragma unroll
    for (int i = 0; i < 8; ++i) { a0[i] = 0.f; a1[i] = 0.f; a2[i] = 0.f; a3[i] = 0.f; }
    if (e == 0) acc8(a0, tab[(size_t)node * FH + q], 1.0f);   // self-loop (w=1)
    int beg = row_ptr[node];
    int end = row_ptr[node + 1];
    int half = (end - beg) >> 1;
    int j = beg + e * half;
    int je = e ? end : (beg + half);
    for (; j + 7 < je; j += 8) {
        int2 p0 = perm[j];
        int2 p1 = perm[j + 1];
        int2 p2 = perm[j + 2];
        int2 p3 = perm[j + 3];
        int2 p4 = perm[j + 4];
        int2 p5 = perm[j + 5];
        int2 p6 = perm[j + 6];
        int2 p7 = perm[j + 7];
        int4 v0 = tab[(size_t)p0.x * FH + q];
        int4 v1 = tab[(size_t)p1.x * FH + q];
        int4 v2 = tab[(size_t)p2.x * FH + q];
        int4 v3 = tab[(size_t)p3.x * FH + q];
        int4 v4 = tab[(size_t)p4.x * FH + q];
        int4 v5 = tab[(size_t)p5.x * FH + q];
        int4 v6 = tab[(size_t)p6.x * FH + q];
        int4 v7 = tab[(size_t)p7.x * FH + q];
        acc8(a0, v0, __int_as_float(p0.y));
        acc8(a1, v1, __int_as_float(p1.y));
        acc8(a2, v2, __int_as_float(p2.y));
        acc8(a3, v3, __int_as_float(p3.y));
        acc8(a0, v4, __int_as_float(p4.y));
        acc8(a1, v5, __int_as_float(p5.y));
        acc8(a2, v6, __int_as_float(p6.y));
        acc8(a3, v7, __int_as_float(p7.y));
    }
    for (; j + 3 < je; j += 4) {
        int2 p0 = perm[j];
        int2 p1 = perm[j + 1];
        int2 p2 = perm[j + 2];
        int2 p3 = perm[j + 3];
        int4 v0 = tab[(size_t)p0.x * FH + q];
        int4 v1 = tab[(size_t)p1.x * FH + q];
        int4 v2 = tab[(size_t)p2.x * FH + q];
        int4 v3 = tab[(size_t)p3.x * FH + q];
        acc8(a0, v0, __int_as_float(p0.y));
        acc8(a1, v1, __int_as_float(p1.y));
        acc8(a2, v2, __int_as_float(p2.y));
        acc8(a3, v3, __int_as_float(p3.y));
    }
    for (; j < je; ++j) {
        int2 p0 = perm[j];
        acc8(a0, tab[(size_t)p0.x * FH + q], __int_as_float(p0.y));
    }
    float r[8];
#pragma unroll
    for (int i = 0; i < 8; ++i) {
        r[i] = (a0[i] + a1[i]) + (a2[i] + a3[i]);
        r[i] += __shfl_xor(r[i], FH);     // merge edge halves
    }
    if (e) return;
    float dv = dinv[node];
    if (HALF_OUT) {
#pragma unroll
        for (int i = 0; i < 8; ++i) {
            float v = r[i] * dv + bias[q * 8 + i];
            v = v > 0.f ? v : expm1f(v);
            r[i] = v * dv;                 // prescale next table
        }
        ((int4*)outv)[(size_t)node * FH + q] = pack8h(r);
    } else {
        float4* o4 = (float4*)outv;
        float4 lo = {r[0] * dv, r[1] * dv, r[2] * dv, r[3] * dv};
        float4 hi = {r[4] * dv, r[5] * dv, r[6] * dv, r[7] * dv};
        size_t base = ((size_t)node * FH + q) * 2;
        o4[base] = lo;
        o4[base + 1] = hi;
    }
}

extern "C" void kernel_launch(void* const* d_in, const int* in_sizes, int n_in,
                              void* d_out, int out_size, void* d_ws, size_t ws_size,
                              hipStream_t stream) {
    const float* x  = (const float*)d_in[0];
    const int*   ei = (const int*)d_in[1];
    const float* w  = (const float*)d_in[2];
    const float* W0 = (const float*)d_in[3];
    const float* b0 = (const float*)d_in[4];
    const float* W1 = (const float*)d_in[5];
    const float* b1 = (const float*)d_in[6];
    const float* W2 = (const float*)d_in[7];
    const float* b2 = (const float*)d_in[8];
    const float* Wm = (const float*)d_in[9];
    const float* bm = (const float*)d_in[10];
    float* out = (float*)d_out;

    const int N = in_sizes[0] / 256;
    const int E = in_sizes[2];
    const int* src = ei;
    const int* dst = ei + E;
    const int nbuck = (N + 255) >> 8;      // 256-node buckets (<=512)

    char* ws = (char*)d_ws;
    size_t off = 0;
    auto alloc = [&](size_t bytes) {
        void* p = ws + off;
        off = (off + bytes + 255) & ~(size_t)255;
        return p;
    };
    float* dinv    = (float*)alloc((size_t)N * 4);
    int*   row_ptr = (int*)alloc(((size_t)N + 1) * 4);
    int*   bcnt    = (int*)alloc(520 * 4);
    int*   boff    = (int*)alloc(520 * 4);
    int*   gcur    = (int*)alloc(520 * 4);
    // bedge region (E*8 bytes), aliased by feature buffers after CSR build:
    char*  regE    = (char*)alloc((size_t)E * 8);
    int2*  perm    = (int2*)alloc((size_t)E * 8);

    int2*  bedge = (int2*)regE;
    size_t eo = 0;
    auto sub = [&](size_t bytes) {
        char* p = regE + eo;
        eo = (eo + bytes + 255) & ~(size_t)255;
        return p;
    };
    __half* T0_h  = (__half*)sub((size_t)N * 16 * 2);   // 3.2MB  dinv*xw
    __half* T1_h  = (__half*)sub((size_t)N * 16 * 2);   // 3.2MB  dinv*h1
    __half* T2_h  = (__half*)sub((size_t)N * 32 * 2);   // 6.4MB  dinv*h2 [N][32]
    float*  AG1_f = (float*)sub((size_t)N * 16 * 4);    // 6.4MB
    float*  AG2_f = (float*)sub((size_t)N * 32 * 4);    // 12.8MB
    float*  H3_f  = (float*)sub((size_t)N * 32 * 4);    // 12.8MB (total ~44.8MB <= E*8)

    hipMemsetAsync(bcnt, 0, 520 * 4, stream);

    const int CH = 8192;
    const int sblk = (E + CH - 1) / CH;

    // ---- build CSR (layer-invariant): perm = (src, w)
    bucket_hist<<<sblk, 256, 0, stream>>>(dst, bcnt, E, nbuck, CH);
    bucket_scan<<<1, 512, 0, stream>>>(bcnt, boff, gcur, nbuck);
    bucket_scatter<<<(E + 4095) / 4096, 512, 0, stream>>>(src, dst, w, gcur, bedge, E);
    bucket_sort<<<nbuck, 1024, 0, stream>>>(boff, bedge, row_ptr, dinv, perm, N, E);
    // bedge dead from here; regE reused for feature buffers.

    const int AGB2 = (N + 63) / 64;     // FH=2: 4 lanes/node
    const int AGB4 = (N + 31) / 32;     // FH=4: 8 lanes/node

    // ---- layer 0: T0 = dinv*(x@W0) fp16 ; T1 = dinv*elu(dinv*sum + b0) fp16
    gemm_x16<<<(N + 15) / 16, 256, 0, stream>>>(x, W0, dinv, T0_h, N);
    agg_es<2, true><<<AGB2, 256, 0, stream>>>(row_ptr, perm, (const int4*)T0_h, dinv, b0, T1_h, N);

    // ---- layer 1: AG1 = dinv*sum(T1) fp32 ; T2 = dinv*elu(AG1@W1+b1) fp16
    agg_es<2, false><<<AGB2, 256, 0, stream>>>(row_ptr, perm, (const int4*)T1_h, dinv, nullptr, AG1_f, N);
    gemm_small<16, 32, true, true><<<(N + 7) / 8, 256, 0, stream>>>(AG1_f, W1, b1, dinv, T2_h, N);

    // ---- layer 2: AG2 = dinv*sum(T2) fp32 ; H3 = elu(AG2@W2+b2) fp32
    agg_es<4, false><<<AGB4, 256, 0, stream>>>(row_ptr, perm, (const int4*)T2_h, dinv, nullptr, AG2_f, N);
    gemm_small<32, 32, true, false><<<(N + 7) / 8, 256, 0, stream>>>(AG2_f, W2, b2, nullptr, H3_f, N);

    // ---- head: out = H3@Wm + bm
    gemm_small<32, 16, false, false><<<(N + 15) / 16, 256, 0, stream>>>(H3_f, Wm, bm, nullptr, out, N);
}

// Round 19
// 444.419 us; speedup vs baseline: 1.0888x; 1.0389x over previous
//
#include <hip/hip_runtime.h>
#include <hip/hip_fp16.h>
#include <cstdint>

// ---------------------------------------------------------------------------
// GCN: 3x GCNConv(+ELU) + linear head.
// Norm factorized: norm = dinv[s]*w*dinv[d]. Gather tables store
// t[n] = dinv[n]*f[n] (fp16); agg computes out = dinv[d]*(t[d] + sum w*t[s]).
// perm = (src, w); build: hist -> scan -> LDS-tile scatter (512 thr, 512
// bins) -> bucket_sort (1024 thr, 4-deep unrolled sweeps).
// Agg: plain-load perm stream + fp16 L2-resident tables + edge-split lanes.
// Round-19: gemm_x16 rewritten with LDS staging (plain coalesced loads; the
// old version used nontemporal loads + 16x redundant row reads and ran at
// 818GB/s / 84us).
// ---------------------------------------------------------------------------

union H2I { __half2 h; int i; };
__device__ inline int h2i(__half2 h) { H2I u; u.h = h; return u.i; }

__device__ inline void acc8(float* a, int4 v, float n) {
    H2I u0, u1, u2, u3;
    u0.i = v.x; u1.i = v.y; u2.i = v.z; u3.i = v.w;
    float2 f0 = __half22float2(u0.h);
    float2 f1 = __half22float2(u1.h);
    float2 f2 = __half22float2(u2.h);
    float2 f3 = __half22float2(u3.h);
    a[0] = fmaf(n, f0.x, a[0]); a[1] = fmaf(n, f0.y, a[1]);
    a[2] = fmaf(n, f1.x, a[2]); a[3] = fmaf(n, f1.y, a[3]);
    a[4] = fmaf(n, f2.x, a[4]); a[5] = fmaf(n, f2.y, a[5]);
    a[6] = fmaf(n, f3.x, a[6]); a[7] = fmaf(n, f3.y, a[7]);
}

__device__ inline int4 pack8h(const float* a) {
    int4 r;
    r.x = h2i(__floats2half2_rn(a[0], a[1]));
    r.y = h2i(__floats2half2_rn(a[2], a[3]));
    r.z = h2i(__floats2half2_rn(a[4], a[5]));
    r.w = h2i(__floats2half2_rn(a[6], a[7]));
    return r;
}

// ---- Pass A: per-bucket edge counts. bucket = dst >> 8.
__global__ void __launch_bounds__(256) bucket_hist(const int* __restrict__ dst,
                                                   int* __restrict__ bcnt,
                                                   int E, int nbuck, int chunk) {
    __shared__ int h[512];
    for (int i = threadIdx.x; i < 512; i += 256) h[i] = 0;
    __syncthreads();
    int c0 = blockIdx.x * chunk;
    int c1 = min(E, c0 + chunk);
    for (int i = c0 + threadIdx.x; i < c1; i += 256)
        atomicAdd(&h[((unsigned)dst[i]) >> 8], 1);
    __syncthreads();
    for (int i = threadIdx.x; i < nbuck; i += 256)
        if (h[i]) atomicAdd(&bcnt[i], h[i]);
}

// ---- scan of bucket counts -> boff[nbuck+1], global cursors.
__global__ void __launch_bounds__(512) bucket_scan(const int* __restrict__ bcnt,
                                                   int* __restrict__ boff,
                                                   int* __restrict__ gcur,
                                                   int nbuck) {
    __shared__ int part[512];
    int t = threadIdx.x;
    part[t] = (t < nbuck) ? bcnt[t] : 0;
    __syncthreads();
    for (int off = 1; off < 512; off <<= 1) {
        int v = part[t];
        int a = (t >= off) ? part[t - off] : 0;
        __syncthreads();
        part[t] = v + a;
        __syncthreads();
    }
    if (t < nbuck) {
        int excl = (t > 0) ? part[t - 1] : 0;
        boff[t] = excl;
        gcur[t] = excl;
        if (t == nbuck - 1) boff[nbuck] = part[t];  // == E
    }
}

// ---- Pass C: LDS counting-sort of 4096-edge tiles (512 thr, 8 edges/thr).
// pack: (local_dst(8b) << 24) | src(24b), payload = w
__global__ void __launch_bounds__(512) bucket_scatter(const int* __restrict__ src,
                                                      const int* __restrict__ dst,
                                                      const float* __restrict__ w,
                                                      int* __restrict__ gcur,
                                                      int2* __restrict__ bedge,
                                                      int E) {
    constexpr int TILE = 4096;
    __shared__ int hc[512];     // histogram, then cursor (local offsets)
    __shared__ int gb[512];
    __shared__ int part[512];
    __shared__ int2 sedge[TILE];
    __shared__ unsigned short sbuck[TILE];

    int t = threadIdx.x;
    int c0 = blockIdx.x * TILE;
    int mtile = min(TILE, E - c0);

    hc[t] = 0;
    __syncthreads();

    int  my_d[8];
    int  my_s[8];
    float my_w[8];
#pragma unroll
    for (int k = 0; k < 2; ++k) {
        int e0 = c0 + (t + k * 512) * 4;
        if (e0 + 4 <= E) {
            int4 d4 = *(const int4*)(dst + e0);
            int4 s4 = *(const int4*)(src + e0);
            float4 w4 = *(const float4*)(w + e0);
            my_d[k*4+0]=d4.x; my_d[k*4+1]=d4.y; my_d[k*4+2]=d4.z; my_d[k*4+3]=d4.w;
            my_s[k*4+0]=s4.x; my_s[k*4+1]=s4.y; my_s[k*4+2]=s4.z; my_s[k*4+3]=s4.w;
            my_w[k*4+0]=w4.x; my_w[k*4+1]=w4.y; my_w[k*4+2]=w4.z; my_w[k*4+3]=w4.w;
        } else {
#pragma unroll
            for (int j = 0; j < 4; ++j) {
                int e = e0 + j;
                bool ok = e < E;
                my_d[k*4+j] = ok ? dst[e] : -1;
                my_s[k*4+j] = ok ? src[e] : 0;
                my_w[k*4+j] = ok ? w[e] : 0.f;
            }
        }
    }
#pragma unroll
    for (int j = 0; j < 8; ++j)
        if (my_d[j] >= 0) atomicAdd(&hc[((unsigned)my_d[j]) >> 8], 1);
    __syncthreads();

    int hb = hc[t];
    part[t] = hb;
    __syncthreads();
    for (int off = 1; off < 512; off <<= 1) {
        int v = part[t];
        int a = (t >= off) ? part[t - off] : 0;
        __syncthreads();
        part[t] = v + a;
        __syncthreads();
    }
    int excl = part[t] - hb;
    hc[t] = excl;                                   // cursor = local offset
    gb[t] = hb ? (atomicAdd(&gcur[t], hb) - excl) : 0;
    __syncthreads();

#pragma unroll
    for (int j = 0; j < 8; ++j) {
        int d = my_d[j];
        if (d < 0) continue;
        unsigned ud = (unsigned)d;
        int b = ud >> 8;
        int p = atomicAdd(&hc[b], 1);
        sedge[p] = make_int2((int)(((ud & 255u) << 24) | (unsigned)my_s[j]),
                             __float_as_int(my_w[j]));
        sbuck[p] = (unsigned short)b;
    }
    __syncthreads();

    for (int i = t; i < mtile; i += 512) {
        int b = sbuck[i];
        bedge[gb[b] + i] = sedge[i];
    }
}

// ---- Pass D (fused, 1024 thr, 4-deep unrolled sweeps): deg -> row_ptr,dinv;
// scatter -> perm=(src,w). Second sweep re-reads the L2-hot bucket run.
__global__ void __launch_bounds__(1024) bucket_sort(const int* __restrict__ boff,
                                                    const int2* __restrict__ bedge,
                                                    int* __restrict__ row_ptr,
                                                    float* __restrict__ dinv,
                                                    int2* __restrict__ perm,
                                                    int N, int E) {
    __shared__ int cnt[256];
    __shared__ float deg[256];
    __shared__ int part[256];
    __shared__ int cur[256];
    int b = blockIdx.x;
    int base = boff[b];
    int m = boff[b + 1] - base;
    int t = threadIdx.x;
    if (t < 256) { cnt[t] = 0; deg[t] = 0.f; }
    __syncthreads();
    int i = t;
    for (; i + 3072 < m; i += 4096) {
        int2 e0 = bedge[base + i];
        int2 e1 = bedge[base + i + 1024];
        int2 e2 = bedge[base + i + 2048];
        int2 e3 = bedge[base + i + 3072];
        atomicAdd(&cnt[((unsigned)e0.x) >> 24], 1);
        atomicAdd(&deg[((unsigned)e0.x) >> 24], __int_as_float(e0.y));
        atomicAdd(&cnt[((unsigned)e1.x) >> 24], 1);
        atomicAdd(&deg[((unsigned)e1.x) >> 24], __int_as_float(e1.y));
        atomicAdd(&cnt[((unsigned)e2.x) >> 24], 1);
        atomicAdd(&deg[((unsigned)e2.x) >> 24], __int_as_float(e2.y));
        atomicAdd(&cnt[((unsigned)e3.x) >> 24], 1);
        atomicAdd(&deg[((unsigned)e3.x) >> 24], __int_as_float(e3.y));
    }
    for (; i < m; i += 1024) {
        int2 e = bedge[base + i];
        unsigned l = ((unsigned)e.x) >> 24;
        atomicAdd(&cnt[l], 1);
        atomicAdd(&deg[l], __int_as_float(e.y));
    }
    __syncthreads();
    if (t < 256) part[t] = cnt[t];
    __syncthreads();
    for (int off = 1; off < 256; off <<= 1) {
        int v = 0, a = 0;
        if (t < 256) { v = part[t]; a = (t >= off) ? part[t - off] : 0; }
        __syncthreads();
        if (t < 256) part[t] = v + a;
        __syncthreads();
    }
    if (t < 256) {
        int excl = part[t] - cnt[t];
        cur[t] = excl;
        int node = b * 256 + t;
        if (node < N) {
            row_ptr[node] = base + excl;
            dinv[node] = rsqrtf(deg[t] + 1.0f);
        }
    }
    if (b == 0 && t == 0) row_ptr[N] = E;
    __syncthreads();
    i = t;
    for (; i + 3072 < m; i += 4096) {
        int2 e0 = bedge[base + i];
        int2 e1 = bedge[base + i + 1024];
        int2 e2 = bedge[base + i + 2048];
        int2 e3 = bedge[base + i + 3072];
        unsigned x0 = (unsigned)e0.x, x1 = (unsigned)e1.x;
        unsigned x2 = (unsigned)e2.x, x3 = (unsigned)e3.x;
        int p0 = base + atomicAdd(&cur[x0 >> 24], 1);
        int p1 = base + atomicAdd(&cur[x1 >> 24], 1);
        int p2 = base + atomicAdd(&cur[x2 >> 24], 1);
        int p3 = base + atomicAdd(&cur[x3 >> 24], 1);
        perm[p0] = make_int2((int)(x0 & 0xFFFFFFu), e0.y);
        perm[p1] = make_int2((int)(x1 & 0xFFFFFFu), e1.y);
        perm[p2] = make_int2((int)(x2 & 0xFFFFFFu), e2.y);
        perm[p3] = make_int2((int)(x3 & 0xFFFFFFu), e3.y);
    }
    for (; i < m; i += 1024) {
        int2 e = bedge[base + i];
        unsigned ux = (unsigned)e.x;
        int pos = base + atomicAdd(&cur[ux >> 24], 1);
        perm[pos] = make_int2((int)(ux & 0xFFFFFFu), e.y);
    }
}

// ---- x[N,256] @ W[256,16], prescaled by dinv[r] -> fp16 [N,16].
// LDS-staged: 16 rows of x (coalesced plain loads) + transposed W.
__global__ void __launch_bounds__(256) gemm_x16(const float* __restrict__ x,
                                                const float* __restrict__ W,
                                                const float* __restrict__ dinv,
                                                __half* __restrict__ xwh, int N) {
    __shared__ float Is[16][260];   // padded: 16B-aligned rows, bank-spread
    __shared__ float Wt[16][260];   // transposed W: Wt[c][k] = W[k*16+c]
    int t = threadIdx.x;
    int r0 = blockIdx.x * 16;
    // stage W transposed
    for (int i = t; i < 4096; i += 256) {
        int k = i >> 4, c = i & 15;
        Wt[c][k] = W[i];
    }
    // stage 16 rows of x, coalesced float4
    const float4* xb = (const float4*)(x + (size_t)r0 * 256);
    for (int i = t; i < 1024; i += 256) {
        int row = i >> 6, k4 = i & 63;
        float4 v;
        if (r0 + row < N) v = xb[(size_t)row * 64 + k4];
        else v = make_float4(0.f, 0.f, 0.f, 0.f);
        *(float4*)&Is[row][k4 * 4] = v;
    }
    __syncthreads();
    int c = t & 15;
    int rl = t >> 4;
    int r = r0 + rl;
    if (r >= N) return;
    float acc = 0.f;
#pragma unroll 16
    for (int k4 = 0; k4 < 64; ++k4) {
        float4 iv = *(const float4*)&Is[rl][k4 * 4];
        float4 wv = *(const float4*)&Wt[c][k4 * 4];
        acc += iv.x * wv.x + iv.y * wv.y + iv.z * wv.z + iv.w * wv.w;
    }
    xwh[(size_t)r * 16 + c] = __float2half_rn(acc * dinv[r]);
}

// in[N,K] @ W[K,F] + bias -> out[N,F]. OUT_ELU: apply ELU.
// HALF_ROW: write fp16 row-major [N][F] prescaled by dinv[r]; else fp32.
template <int K, int F, bool OUT_ELU, bool HALF_ROW>
__global__ void __launch_bounds__(256) gemm_small(const float* __restrict__ in,
                                                  const float* __restrict__ W,
                                                  const float* __restrict__ bias,
                                                  const float* __restrict__ dinv,
                                                  void* __restrict__ outv, int N) {
    constexpr int ROWS = 256 / F;
    __shared__ float Ws[K * F];
    __shared__ float Is[ROWS * K];
    for (int i = threadIdx.x; i < K * F; i += 256) Ws[i] = W[i];
    int r0 = blockIdx.x * ROWS;
    for (int i = threadIdx.x; i < ROWS * K; i += 256)
        Is[i] = in[(size_t)r0 * K + i];
    __syncthreads();
    int c = threadIdx.x % F;
    int rl = threadIdx.x / F;
    int r = r0 + rl;
    float acc = bias[c];
#pragma unroll
    for (int k = 0; k < K; ++k) acc += Is[rl * K + k] * Ws[k * F + c];
    if (OUT_ELU) acc = acc > 0.f ? acc : expm1f(acc);
    if (HALF_ROW) {
        ((__half*)outv)[(size_t)r * F + c] = __float2half_rn(acc * dinv[r]);
    } else {
        ((float*)outv)[(size_t)r * F + c] = acc;
    }
}

// ---- fp16 prescaled-table gather-aggregate with edge-split lanes.
// Table: t[n] = dinv[n]*f[n], fp16 row-major [N][8*FH] (int4 = node*FH + q).
// Lanes/node = FH*2: q = feature chunk, e = edge half; shfl_xor(FH) merges.
// Math: sum = t[node] + sum_e w_e * t[src_e]; out = dinv[node]*sum [+b, ELU].
template <int FH, bool HALF_OUT>
__global__ void __launch_bounds__(256) agg_es(const int* __restrict__ row_ptr,
                                              const int2* __restrict__ perm,
                                              const int4* __restrict__ tab,
                                              const float* __restrict__ dinv,
                                              const float* __restrict__ bias,
                                              void* __restrict__ outv, int N) {
    constexpr int LPN = FH * 2;
    constexpr int NPB = 256 / LPN;
    int node = blockIdx.x * NPB + threadIdx.x / LPN;
    int sub = threadIdx.x % LPN;
    int q = sub % FH;
    int e = sub / FH;
    if (node >= N) return;
    float a0[8], a1[8], a2[8], a3[8];
#pragma unroll
    for (int i = 0; i < 8; ++i) { a0[i] = 0.f; a1[i] = 0.f; a2[i] = 0.f; a3[i] = 0.f; }
    if (e == 0) acc8(a0, tab[(size_t)node * FH + q], 1.0f);   // self-loop (w=1)
    int beg = row_ptr[node];
    int end = row_ptr[node + 1];
    int half = (end - beg) >> 1;
    int j = beg + e * half;
    int je = e ? end : (beg + half);
    for (; j + 7 < je; j += 8) {
        int2 p0 = perm[j];
        int2 p1 = perm[j + 1];
        int2 p2 = perm[j + 2];
        int2 p3 = perm[j + 3];
        int2 p4 = perm[j + 4];
        int2 p5 = perm[j + 5];
        int2 p6 = perm[j + 6];
        int2 p7 = perm[j + 7];
        int4 v0 = tab[(size_t)p0.x * FH + q];
        int4 v1 = tab[(size_t)p1.x * FH + q];
        int4 v2 = tab[(size_t)p2.x * FH + q];
        int4 v3 = tab[(size_t)p3.x * FH + q];
        int4 v4 = tab[(size_t)p4.x * FH + q];
        int4 v5 = tab[(size_t)p5.x * FH + q];
        int4 v6 = tab[(size_t)p6.x * FH + q];
        int4 v7 = tab[(size_t)p7.x * FH + q];
        acc8(a0, v0, __int_as_float(p0.y));
        acc8(a1, v1, __int_as_float(p1.y));
        acc8(a2, v2, __int_as_float(p2.y));
        acc8(a3, v3, __int_as_float(p3.y));
        acc8(a0, v4, __int_as_float(p4.y));
        acc8(a1, v5, __int_as_float(p5.y));
        acc8(a2, v6, __int_as_float(p6.y));
        acc8(a3, v7, __int_as_float(p7.y));
    }
    for (; j + 3 < je; j += 4) {
        int2 p0 = perm[j];
        int2 p1 = perm[j + 1];
        int2 p2 = perm[j + 2];
        int2 p3 = perm[j + 3];
        int4 v0 = tab[(size_t)p0.x * FH + q];
        int4 v1 = tab[(size_t)p1.x * FH + q];
        int4 v2 = tab[(size_t)p2.x * FH + q];
        int4 v3 = tab[(size_t)p3.x * FH + q];
        acc8(a0, v0, __int_as_float(p0.y));
        acc8(a1, v1, __int_as_float(p1.y));
        acc8(a2, v2, __int_as_float(p2.y));
        acc8(a3, v3, __int_as_float(p3.y));
    }
    for (; j < je; ++j) {
        int2 p0 = perm[j];
        acc8(a0, tab[(size_t)p0.x * FH + q], __int_as_float(p0.y));
    }
    float r[8];
#pragma unroll
    for (int i = 0; i < 8; ++i) {
        r[i] = (a0[i] + a1[i]) + (a2[i] + a3[i]);
        r[i] += __shfl_xor(r[i], FH);     // merge edge halves
    }
    if (e) return;
    float dv = dinv[node];
    if (HALF_OUT) {
#pragma unroll
        for (int i = 0; i < 8; ++i) {
            float v = r[i] * dv + bias[q * 8 + i];
            v = v > 0.f ? v : expm1f(v);
            r[i] = v * dv;                 // prescale next table
        }
        ((int4*)outv)[(size_t)node * FH + q] = pack8h(r);
    } else {
        float4* o4 = (float4*)outv;
        float4 lo = {r[0] * dv, r[1] * dv, r[2] * dv, r[3] * dv};
        float4 hi = {r[4] * dv, r[5] * dv, r[6] * dv, r[7] * dv};
        size_t base = ((size_t)node * FH + q) * 2;
        o4[base] = lo;
        o4[base + 1] = hi;
    }
}

extern "C" void kernel_launch(void* const* d_in, const int* in_sizes, int n_in,
                              void* d_out, int out_size, void* d_ws, size_t ws_size,
                              hipStream_t stream) {
    const float* x  = (const float*)d_in[0];
    const int*   ei = (const int*)d_in[1];
    const float* w  = (const float*)d_in[2];
    const float* W0 = (const float*)d_in[3];
    const float* b0 = (const float*)d_in[4];
    const float* W1 = (const float*)d_in[5];
    const float* b1 = (const float*)d_in[6];
    const float* W2 = (const float*)d_in[7];
    const float* b2 = (const float*)d_in[8];
    const float* Wm = (const float*)d_in[9];
    const float* bm = (const float*)d_in[10];
    float* out = (float*)d_out;

    const int N = in_sizes[0] / 256;
    const int E = in_sizes[2];
    const int* src = ei;
    const int* dst = ei + E;
    const int nbuck = (N + 255) >> 8;      // 256-node buckets (<=512)

    char* ws = (char*)d_ws;
    size_t off = 0;
    auto alloc = [&](size_t bytes) {
        void* p = ws + off;
        off = (off + bytes + 255) & ~(size_t)255;
        return p;
    };
    float* dinv    = (float*)alloc((size_t)N * 4);
    int*   row_ptr = (int*)alloc(((size_t)N + 1) * 4);
    int*   bcnt    = (int*)alloc(520 * 4);
    int*   boff    = (int*)alloc(520 * 4);
    int*   gcur    = (int*)alloc(520 * 4);
    // bedge region (E*8 bytes), aliased by feature buffers after CSR build:
    char*  regE    = (char*)alloc((size_t)E * 8);
    int2*  perm    = (int2*)alloc((size_t)E * 8);

    int2*  bedge = (int2*)regE;
    size_t eo = 0;
    auto sub = [&](size_t bytes) {
        char* p = regE + eo;
        eo = (eo + bytes + 255) & ~(size_t)255;
        return p;
    };
    __half* T0_h  = (__half*)sub((size_t)N * 16 * 2);   // 3.2MB  dinv*xw
    __half* T1_h  = (__half*)sub((size_t)N * 16 * 2);   // 3.2MB  dinv*h1
    __half* T2_h  = (__half*)sub((size_t)N * 32 * 2);   // 6.4MB  dinv*h2 [N][32]
    float*  AG1_f = (float*)sub((size_t)N * 16 * 4);    // 6.4MB
    float*  AG2_f = (float*)sub((size_t)N * 32 * 4);    // 12.8MB
    float*  H3_f  = (float*)sub((size_t)N * 32 * 4);    // 12.8MB (total ~44.8MB <= E*8)

    hipMemsetAsync(bcnt, 0, 520 * 4, stream);

    const int CH = 8192;
    const int sblk = (E + CH - 1) / CH;

    // ---- build CSR (layer-invariant): perm = (src, w)
    bucket_hist<<<sblk, 256, 0, stream>>>(dst, bcnt, E, nbuck, CH);
    bucket_scan<<<1, 512, 0, stream>>>(bcnt, boff, gcur, nbuck);
    bucket_scatter<<<(E + 4095) / 4096, 512, 0, stream>>>(src, dst, w, gcur, bedge, E);
    bucket_sort<<<nbuck, 1024, 0, stream>>>(boff, bedge, row_ptr, dinv, perm, N, E);
    // bedge dead from here; regE reused for feature buffers.

    const int AGB2 = (N + 63) / 64;     // FH=2: 4 lanes/node
    const int AGB4 = (N + 31) / 32;     // FH=4: 8 lanes/node

    // ---- layer 0: T0 = dinv*(x@W0) fp16 ; T1 = dinv*elu(dinv*sum + b0) fp16
    gemm_x16<<<(N + 15) / 16, 256, 0, stream>>>(x, W0, dinv, T0_h, N);
    agg_es<2, true><<<AGB2, 256, 0, stream>>>(row_ptr, perm, (const int4*)T0_h, dinv, b0, T1_h, N);

    // ---- layer 1: AG1 = dinv*sum(T1) fp32 ; T2 = dinv*elu(AG1@W1+b1) fp16
    agg_es<2, false><<<AGB2, 256, 0, stream>>>(row_ptr, perm, (const int4*)T1_h, dinv, nullptr, AG1_f, N);
    gemm_small<16, 32, true, true><<<(N + 7) / 8, 256, 0, stream>>>(AG1_f, W1, b1, dinv, T2_h, N);

    // ---- layer 2: AG2 = dinv*sum(T2) fp32 ; H3 = elu(AG2@W2+b2) fp32
    agg_es<4, false><<<AGB4, 256, 0, stream>>>(row_ptr, perm, (const int4*)T2_h, dinv, nullptr, AG2_f, N);
    gemm_small<32, 32, true, false><<<(N + 7) / 8, 256, 0, stream>>>(AG2_f, W2, b2, nullptr, H3_f, N);

    // ---- head: out = H3@Wm + bm
    gemm_small<32, 16, false, false><<<(N + 15) / 16, 256, 0, stream>>>(H3_f, Wm, bm, nullptr, out, N);
}

// Round 20
// 412.995 us; speedup vs baseline: 1.1717x; 1.0761x over previous
//
#include <hip/hip_runtime.h>
#include <hip/hip_fp16.h>
#include <cstdint>

// ---------------------------------------------------------------------------
// GCN: 3x GCNConv(+ELU) + linear head.
// Norm factorized: norm = dinv[s]*w*dinv[d]. Gather tables store
// t[n] = dinv[n]*f[n] (fp16); agg computes out = dinv[d]*(t[d] + sum w*t[s]).
// perm = (src, w); build: hist(int4 loads) -> scan -> LDS-tile scatter
// (wave-shfl scan, 2 barriers) -> bucket_sort (packed 64-bit cnt+deg atomic,
// wave-shfl scan, 4-deep unrolled sweeps).
// Agg: plain-load perm stream + fp16 L2-resident tables + edge-split lanes
// (at the measured ~3.3TB/s scattered-gather ceiling; unchanged).
// ---------------------------------------------------------------------------

union H2I { __half2 h; int i; };
__device__ inline int h2i(__half2 h) { H2I u; u.h = h; return u.i; }

__device__ inline void acc8(float* a, int4 v, float n) {
    H2I u0, u1, u2, u3;
    u0.i = v.x; u1.i = v.y; u2.i = v.z; u3.i = v.w;
    float2 f0 = __half22float2(u0.h);
    float2 f1 = __half22float2(u1.h);
    float2 f2 = __half22float2(u2.h);
    float2 f3 = __half22float2(u3.h);
    a[0] = fmaf(n, f0.x, a[0]); a[1] = fmaf(n, f0.y, a[1]);
    a[2] = fmaf(n, f1.x, a[2]); a[3] = fmaf(n, f1.y, a[3]);
    a[4] = fmaf(n, f2.x, a[4]); a[5] = fmaf(n, f2.y, a[5]);
    a[6] = fmaf(n, f3.x, a[6]); a[7] = fmaf(n, f3.y, a[7]);
}

__device__ inline int4 pack8h(const float* a) {
    int4 r;
    r.x = h2i(__floats2half2_rn(a[0], a[1]));
    r.y = h2i(__floats2half2_rn(a[2], a[3]));
    r.z = h2i(__floats2half2_rn(a[4], a[5]));
    r.w = h2i(__floats2half2_rn(a[6], a[7]));
    return r;
}

// inclusive wave scan (64 lanes)
__device__ inline int wave_iscan(int v, int lane) {
#pragma unroll
    for (int off = 1; off < 64; off <<= 1) {
        int u = __shfl_up(v, off);
        if (lane >= off) v += u;
    }
    return v;
}

// ---- Pass A: per-bucket edge counts. bucket = dst >> 8. int4 loads.
__global__ void __launch_bounds__(256) bucket_hist(const int* __restrict__ dst,
                                                   int* __restrict__ bcnt,
                                                   int E, int nbuck, int chunk) {
    __shared__ int h[512];
    for (int i = threadIdx.x; i < 512; i += 256) h[i] = 0;
    __syncthreads();
    const int4* d4 = (const int4*)dst;
    int q0 = (blockIdx.x * chunk) >> 2;
    int q1 = min(E >> 2, q0 + (chunk >> 2));
    for (int i = q0 + threadIdx.x; i < q1; i += 256) {
        int4 v = d4[i];
        atomicAdd(&h[((unsigned)v.x) >> 8], 1);
        atomicAdd(&h[((unsigned)v.y) >> 8], 1);
        atomicAdd(&h[((unsigned)v.z) >> 8], 1);
        atomicAdd(&h[((unsigned)v.w) >> 8], 1);
    }
    if (blockIdx.x == 0) {  // tail (E % 4)
        for (int e = (E & ~3) + threadIdx.x; e < E; e += 256)
            atomicAdd(&h[((unsigned)dst[e]) >> 8], 1);
    }
    __syncthreads();
    for (int i = threadIdx.x; i < nbuck; i += 256)
        if (h[i]) atomicAdd(&bcnt[i], h[i]);
}

// ---- scan of bucket counts -> boff[nbuck+1], global cursors.
__global__ void __launch_bounds__(512) bucket_scan(const int* __restrict__ bcnt,
                                                   int* __restrict__ boff,
                                                   int* __restrict__ gcur,
                                                   int nbuck) {
    __shared__ int part[512];
    int t = threadIdx.x;
    part[t] = (t < nbuck) ? bcnt[t] : 0;
    __syncthreads();
    for (int off = 1; off < 512; off <<= 1) {
        int v = part[t];
        int a = (t >= off) ? part[t - off] : 0;
        __syncthreads();
        part[t] = v + a;
        __syncthreads();
    }
    if (t < nbuck) {
        int excl = (t > 0) ? part[t - 1] : 0;
        boff[t] = excl;
        gcur[t] = excl;
        if (t == nbuck - 1) boff[nbuck] = part[t];  // == E
    }
}

// ---- Pass C: LDS counting-sort of 4096-edge tiles (512 thr, wave-shfl scan).
// pack: (local_dst(8b) << 24) | src(24b), payload = w
__global__ void __launch_bounds__(512) bucket_scatter(const int* __restrict__ src,
                                                      const int* __restrict__ dst,
                                                      const float* __restrict__ w,
                                                      int* __restrict__ gcur,
                                                      int2* __restrict__ bedge,
                                                      int E) {
    constexpr int TILE = 4096;
    __shared__ int hc[512];     // histogram, then cursor (local offsets)
    __shared__ int gb[512];
    __shared__ int wsum[8];
    __shared__ int2 sedge[TILE];
    __shared__ unsigned short sbuck[TILE];

    int t = threadIdx.x;
    int c0 = blockIdx.x * TILE;
    int mtile = min(TILE, E - c0);

    hc[t] = 0;
    __syncthreads();

    int  my_d[8];
    int  my_s[8];
    float my_w[8];
#pragma unroll
    for (int k = 0; k < 2; ++k) {
        int e0 = c0 + (t + k * 512) * 4;
        if (e0 + 4 <= E) {
            int4 d4 = *(const int4*)(dst + e0);
            int4 s4 = *(const int4*)(src + e0);
            float4 w4 = *(const float4*)(w + e0);
            my_d[k*4+0]=d4.x; my_d[k*4+1]=d4.y; my_d[k*4+2]=d4.z; my_d[k*4+3]=d4.w;
            my_s[k*4+0]=s4.x; my_s[k*4+1]=s4.y; my_s[k*4+2]=s4.z; my_s[k*4+3]=s4.w;
            my_w[k*4+0]=w4.x; my_w[k*4+1]=w4.y; my_w[k*4+2]=w4.z; my_w[k*4+3]=w4.w;
        } else {
#pragma unroll
            for (int j = 0; j < 4; ++j) {
                int e = e0 + j;
                bool ok = e < E;
                my_d[k*4+j] = ok ? dst[e] : -1;
                my_s[k*4+j] = ok ? src[e] : 0;
                my_w[k*4+j] = ok ? w[e] : 0.f;
            }
        }
    }
#pragma unroll
    for (int j = 0; j < 8; ++j)
        if (my_d[j] >= 0) atomicAdd(&hc[((unsigned)my_d[j]) >> 8], 1);
    __syncthreads();

    // wave-level scan of hc[512] (8 waves), 2 barriers
    int hb = hc[t];
    int lane = t & 63;
    int wid = t >> 6;
    int isc = wave_iscan(hb, lane);
    if (lane == 63) wsum[wid] = isc;
    __syncthreads();
    if (t < 8) {
        int v = wsum[t];
#pragma unroll
        for (int off = 1; off < 8; off <<= 1) {
            int u = __shfl_up(v, off);
            if (t >= off) v += u;
        }
        wsum[t] = v;
    }
    __syncthreads();
    int excl = (wid ? wsum[wid - 1] : 0) + isc - hb;
    hc[t] = excl;                                   // cursor = local offset
    gb[t] = hb ? (atomicAdd(&gcur[t], hb) - excl) : 0;
    __syncthreads();

#pragma unroll
    for (int j = 0; j < 8; ++j) {
        int d = my_d[j];
        if (d < 0) continue;
        unsigned ud = (unsigned)d;
        int b = ud >> 8;
        int p = atomicAdd(&hc[b], 1);
        sedge[p] = make_int2((int)(((ud & 255u) << 24) | (unsigned)my_s[j]),
                             __float_as_int(my_w[j]));
        sbuck[p] = (unsigned short)b;
    }
    __syncthreads();

    for (int i = t; i < mtile; i += 512) {
        int b = sbuck[i];
        bedge[gb[b] + i] = sedge[i];
    }
}

// ---- Pass D (fused, 1024 thr): sweep 1 uses ONE packed 64-bit LDS atomic
// per edge (count in bits 42+, w fixed-point 2^-24 in low bits); wave-shfl
// scan; sweep 2 scatters perm=(src,w) with 4-deep unroll.
__global__ void __launch_bounds__(1024) bucket_sort(const int* __restrict__ boff,
                                                    const int2* __restrict__ bedge,
                                                    int* __restrict__ row_ptr,
                                                    float* __restrict__ dinv,
                                                    int2* __restrict__ perm,
                                                    int N, int E) {
    __shared__ unsigned long long pack[256];
    __shared__ int cur[256];
    __shared__ int wsum[4];
    int b = blockIdx.x;
    int base = boff[b];
    int m = boff[b + 1] - base;
    int t = threadIdx.x;
    if (t < 256) pack[t] = 0ull;
    __syncthreads();
    const float FIX = 16777216.0f;  // 2^24
    int i = t;
    for (; i + 3072 < m; i += 4096) {
        int2 e0 = bedge[base + i];
        int2 e1 = bedge[base + i + 1024];
        int2 e2 = bedge[base + i + 2048];
        int2 e3 = bedge[base + i + 3072];
        atomicAdd(&pack[((unsigned)e0.x) >> 24],
                  (1ull << 42) | (unsigned long long)(unsigned)(__int_as_float(e0.y) * FIX));
        atomicAdd(&pack[((unsigned)e1.x) >> 24],
                  (1ull << 42) | (unsigned long long)(unsigned)(__int_as_float(e1.y) * FIX));
        atomicAdd(&pack[((unsigned)e2.x) >> 24],
                  (1ull << 42) | (unsigned long long)(unsigned)(__int_as_float(e2.y) * FIX));
        atomicAdd(&pack[((unsigned)e3.x) >> 24],
                  (1ull << 42) | (unsigned long long)(unsigned)(__int_as_float(e3.y) * FIX));
    }
    for (; i < m; i += 1024) {
        int2 e = bedge[base + i];
        atomicAdd(&pack[((unsigned)e.x) >> 24],
                  (1ull << 42) | (unsigned long long)(unsigned)(__int_as_float(e.y) * FIX));
    }
    __syncthreads();
    // wave-level scan of counts (first 256 threads = 4 waves), 2 barriers
    int cnt_t = 0, isc = 0;
    int lane = t & 63;
    int wid = t >> 6;
    if (t < 256) {
        cnt_t = (int)(pack[t] >> 42);
        isc = wave_iscan(cnt_t, lane);
        if (lane == 63) wsum[wid] = isc;
    }
    __syncthreads();
    if (t < 4) {
        int v = wsum[t];
#pragma unroll
        for (int off = 1; off < 4; off <<= 1) {
            int u = __shfl_up(v, off);
            if (t >= off) v += u;
        }
        wsum[t] = v;
    }
    __syncthreads();
    if (t < 256) {
        int excl = (wid ? wsum[wid - 1] : 0) + isc - cnt_t;
        cur[t] = excl;
        int node = b * 256 + t;
        if (node < N) {
            row_ptr[node] = base + excl;
            float deg = (float)(pack[t] & ((1ull << 42) - 1)) * 5.9604644775390625e-08f;
            dinv[node] = rsqrtf(deg + 1.0f);
        }
    }
    if (b == 0 && t == 0) row_ptr[N] = E;
    __syncthreads();
    i = t;
    for (; i + 3072 < m; i += 4096) {
        int2 e0 = bedge[base + i];
        int2 e1 = bedge[base + i + 1024];
        int2 e2 = bedge[base + i + 2048];
        int2 e3 = bedge[base + i + 3072];
        unsigned x0 = (unsigned)e0.x, x1 = (unsigned)e1.x;
        unsigned x2 = (unsigned)e2.x, x3 = (unsigned)e3.x;
        int p0 = base + atomicAdd(&cur[x0 >> 24], 1);
        int p1 = base + atomicAdd(&cur[x1 >> 24], 1);
        int p2 = base + atomicAdd(&cur[x2 >> 24], 1);
        int p3 = base + atomicAdd(&cur[x3 >> 24], 1);
        perm[p0] = make_int2((int)(x0 & 0xFFFFFFu), e0.y);
        perm[p1] = make_int2((int)(x1 & 0xFFFFFFu), e1.y);
        perm[p2] = make_int2((int)(x2 & 0xFFFFFFu), e2.y);
        perm[p3] = make_int2((int)(x3 & 0xFFFFFFu), e3.y);
    }
    for (; i < m; i += 1024) {
        int2 e = bedge[base + i];
        unsigned ux = (unsigned)e.x;
        int pos = base + atomicAdd(&cur[ux >> 24], 1);
        perm[pos] = make_int2((int)(ux & 0xFFFFFFu), e.y);
    }
}

// ---- x[N,256] @ W[256,16], prescaled by dinv[r] -> fp16 [N,16].
// LDS-staged: 16 rows of x (coalesced plain loads) + transposed W.
__global__ void __launch_bounds__(256) gemm_x16(const float* __restrict__ x,
                                                const float* __restrict__ W,
                                                const float* __restrict__ dinv,
                                                __half* __restrict__ xwh, int N) {
    __shared__ float Is[16][260];
    __shared__ float Wt[16][260];
    int t = threadIdx.x;
    int r0 = blockIdx.x * 16;
    for (int i = t; i < 4096; i += 256) {
        int k = i >> 4, c = i & 15;
        Wt[c][k] = W[i];
    }
    const float4* xb = (const float4*)(x + (size_t)r0 * 256);
    for (int i = t; i < 1024; i += 256) {
        int row = i >> 6, k4 = i & 63;
        float4 v;
        if (r0 + row < N) v = xb[(size_t)row * 64 + k4];
        else v = make_float4(0.f, 0.f, 0.f, 0.f);
        *(float4*)&Is[row][k4 * 4] = v;
    }
    __syncthreads();
    int c = t & 15;
    int rl = t >> 4;
    int r = r0 + rl;
    if (r >= N) return;
    float acc = 0.f;
#pragma unroll 16
    for (int k4 = 0; k4 < 64; ++k4) {
        float4 iv = *(const float4*)&Is[rl][k4 * 4];
        float4 wv = *(const float4*)&Wt[c][k4 * 4];
        acc += iv.x * wv.x + iv.y * wv.y + iv.z * wv.z + iv.w * wv.w;
    }
    xwh[(size_t)r * 16 + c] = __float2half_rn(acc * dinv[r]);
}

// in[N,K] @ W[K,F] + bias -> out[N,F]. OUT_ELU: apply ELU.
// HALF_ROW: write fp16 row-major [N][F] prescaled by dinv[r]; else fp32.
template <int K, int F, bool OUT_ELU, bool HALF_ROW>
__global__ void __launch_bounds__(256) gemm_small(const float* __restrict__ in,
                                                  const float* __restrict__ W,
                                                  const float* __restrict__ bias,
                                                  const float* __restrict__ dinv,
                                                  void* __restrict__ outv, int N) {
    constexpr int ROWS = 256 / F;
    __shared__ float Ws[K * F];
    __shared__ float Is[ROWS * K];
    for (int i = threadIdx.x; i < K * F; i += 256) Ws[i] = W[i];
    int r0 = blockIdx.x * ROWS;
    for (int i = threadIdx.x; i < ROWS * K; i += 256)
        Is[i] = in[(size_t)r0 * K + i];
    __syncthreads();
    int c = threadIdx.x % F;
    int rl = threadIdx.x / F;
    int r = r0 + rl;
    float acc = bias[c];
#pragma unroll
    for (int k = 0; k < K; ++k) acc += Is[rl * K + k] * Ws[k * F + c];
    if (OUT_ELU) acc = acc > 0.f ? acc : expm1f(acc);
    if (HALF_ROW) {
        ((__half*)outv)[(size_t)r * F + c] = __float2half_rn(acc * dinv[r]);
    } else {
        ((float*)outv)[(size_t)r * F + c] = acc;
    }
}

// ---- fp16 prescaled-table gather-aggregate with edge-split lanes.
// Table: t[n] = dinv[n]*f[n], fp16 row-major [N][8*FH] (int4 = node*FH + q).
// Lanes/node = FH*2: q = feature chunk, e = edge half; shfl_xor(FH) merges.
// Math: sum = t[node] + sum_e w_e * t[src_e]; out = dinv[node]*sum [+b, ELU].
template <int FH, bool HALF_OUT>
__global__ void __launch_bounds__(256) agg_es(const int* __restrict__ row_ptr,
                                              const int2* __restrict__ perm,
                                              const int4* __restrict__ tab,
                                              const float* __restrict__ dinv,
                                              const float* __restrict__ bias,
                                              void* __restrict__ outv, int N) {
    constexpr int LPN = FH * 2;
    constexpr int NPB = 256 / LPN;
    int node = blockIdx.x * NPB + threadIdx.x / LPN;
    int sub = threadIdx.x % LPN;
    int q = sub % FH;
    int e = sub / FH;
    if (node >= N) return;
    float a0[8], a1[8], a2[8], a3[8];
#pragma unroll
    for (int i = 0; i < 8; ++i) { a0[i] = 0.f; a1[i] = 0.f; a2[i] = 0.f; a3[i] = 0.f; }
    if (e == 0) acc8(a0, tab[(size_t)node * FH + q], 1.0f);   // self-loop (w=1)
    int beg = row_ptr[node];
    int end = row_ptr[node + 1];
    int half = (end - beg) >> 1;
    int j = beg + e * half;
    int je = e ? end : (beg + half);
    for (; j + 7 < je; j += 8) {
        int2 p0 = perm[j];
        int2 p1 = perm[j + 1];
        int2 p2 = perm[j + 2];
        int2 p3 = perm[j + 3];
        int2 p4 = perm[j + 4];
        int2 p5 = perm[j + 5];
        int2 p6 = perm[j + 6];
        int2 p7 = perm[j + 7];
        int4 v0 = tab[(size_t)p0.x * FH + q];
        int4 v1 = tab[(size_t)p1.x * FH + q];
        int4 v2 = tab[(size_t)p2.x * FH + q];
        int4 v3 = tab[(size_t)p3.x * FH + q];
        int4 v4 = tab[(size_t)p4.x * FH + q];
        int4 v5 = tab[(size_t)p5.x * FH + q];
        int4 v6 = tab[(size_t)p6.x * FH + q];
        int4 v7 = tab[(size_t)p7.x * FH + q];
        acc8(a0, v0, __int_as_float(p0.y));
        acc8(a1, v1, __int_as_float(p1.y));
        acc8(a2, v2, __int_as_float(p2.y));
        acc8(a3, v3, __int_as_float(p3.y));
        acc8(a0, v4, __int_as_float(p4.y));
        acc8(a1, v5, __int_as_float(p5.y));
        acc8(a2, v6, __int_as_float(p6.y));
        acc8(a3, v7, __int_as_float(p7.y));
    }
    for (; j + 3 < je; j += 4) {
        int2 p0 = perm[j];
        int2 p1 = perm[j + 1];
        int2 p2 = perm[j + 2];
        int2 p3 = perm[j + 3];
        int4 v0 = tab[(size_t)p0.x * FH + q];
        int4 v1 = tab[(size_t)p1.x * FH + q];
        int4 v2 = tab[(size_t)p2.x * FH + q];
        int4 v3 = tab[(size_t)p3.x * FH + q];
        acc8(a0, v0, __int_as_float(p0.y));
        acc8(a1, v1, __int_as_float(p1.y));
        acc8(a2, v2, __int_as_float(p2.y));
        acc8(a3, v3, __int_as_float(p3.y));
    }
    for (; j < je; ++j) {
        int2 p0 = perm[j];
        acc8(a0, tab[(size_t)p0.x * FH + q], __int_as_float(p0.y));
    }
    float r[8];
#pragma unroll
    for (int i = 0; i < 8; ++i) {
        r[i] = (a0[i] + a1[i]) + (a2[i] + a3[i]);
        r[i] += __shfl_xor(r[i], FH);     // merge edge halves
    }
    if (e) return;
    float dv = dinv[node];
    if (HALF_OUT) {
#pragma unroll
        for (int i = 0; i < 8; ++i) {
            float v = r[i] * dv + bias[q * 8 + i];
            v = v > 0.f ? v : expm1f(v);
            r[i] = v * dv;                 // prescale next table
        }
        ((int4*)outv)[(size_t)node * FH + q] = pack8h(r);
    } else {
        float4* o4 = (float4*)outv;
        float4 lo = {r[0] * dv, r[1] * dv, r[2] * dv, r[3] * dv};
        float4 hi = {r[4] * dv, r[5] * dv, r[6] * dv, r[7] * dv};
        size_t base = ((size_t)node * FH + q) * 2;
        o4[base] = lo;
        o4[base + 1] = hi;
    }
}

extern "C" void kernel_launch(void* const* d_in, const int* in_sizes, int n_in,
                              void* d_out, int out_size, void* d_ws, size_t ws_size,
                              hipStream_t stream) {
    const float* x  = (const float*)d_in[0];
    const int*   ei = (const int*)d_in[1];
    const float* w  = (const float*)d_in[2];
    const float* W0 = (const float*)d_in[3];
    const float* b0 = (const float*)d_in[4];
    const float* W1 = (const float*)d_in[5];
    const float* b1 = (const float*)d_in[6];
    const float* W2 = (const float*)d_in[7];
    const float* b2 = (const float*)d_in[8];
    const float* Wm = (const float*)d_in[9];
    const float* bm = (const float*)d_in[10];
    float* out = (float*)d_out;

    const int N = in_sizes[0] / 256;
    const int E = in_sizes[2];
    const int* src = ei;
    const int* dst = ei + E;
    const int nbuck = (N + 255) >> 8;      // 256-node buckets (<=512)

    char* ws = (char*)d_ws;
    size_t off = 0;
    auto alloc = [&](size_t bytes) {
        void* p = ws + off;
        off = (off + bytes + 255) & ~(size_t)255;
        return p;
    };
    float* dinv    = (float*)alloc((size_t)N * 4);
    int*   row_ptr = (int*)alloc(((size_t)N + 1) * 4);
    int*   bcnt    = (int*)alloc(520 * 4);
    int*   boff    = (int*)alloc(520 * 4);
    int*   gcur    = (int*)alloc(520 * 4);
    // bedge region (E*8 bytes), aliased by feature buffers after CSR build:
    char*  regE    = (char*)alloc((size_t)E * 8);
    int2*  perm    = (int2*)alloc((size_t)E * 8);

    int2*  bedge = (int2*)regE;
    size_t eo = 0;
    auto sub = [&](size_t bytes) {
        char* p = regE + eo;
        eo = (eo + bytes + 255) & ~(size_t)255;
        return p;
    };
    __half* T0_h  = (__half*)sub((size_t)N * 16 * 2);   // 3.2MB  dinv*xw
    __half* T1_h  = (__half*)sub((size_t)N * 16 * 2);   // 3.2MB  dinv*h1
    __half* T2_h  = (__half*)sub((size_t)N * 32 * 2);   // 6.4MB  dinv*h2 [N][32]
    float*  AG1_f = (float*)sub((size_t)N * 16 * 4);    // 6.4MB
    float*  AG2_f = (float*)sub((size_t)N * 32 * 4);    // 12.8MB
    float*  H3_f  = (float*)sub((size_t)N * 32 * 4);    // 12.8MB (total ~44.8MB <= E*8)

    hipMemsetAsync(bcnt, 0, 520 * 4, stream);

    const int CH = 8192;
    const int sblk = (E + CH - 1) / CH;

    // ---- build CSR (layer-invariant): perm = (src, w)
    bucket_hist<<<sblk, 256, 0, stream>>>(dst, bcnt, E, nbuck, CH);
    bucket_scan<<<1, 512, 0, stream>>>(bcnt, boff, gcur, nbuck);
    bucket_scatter<<<(E + 4095) / 4096, 512, 0, stream>>>(src, dst, w, gcur, bedge, E);
    bucket_sort<<<nbuck, 1024, 0, stream>>>(boff, bedge, row_ptr, dinv, perm, N, E);
    // bedge dead from here; regE reused for feature buffers.

    const int AGB2 = (N + 63) / 64;     // FH=2: 4 lanes/node
    const int AGB4 = (N + 31) / 32;     // FH=4: 8 lanes/node

    // ---- layer 0: T0 = dinv*(x@W0) fp16 ; T1 = dinv*elu(dinv*sum + b0) fp16
    gemm_x16<<<(N + 15) / 16, 256, 0, stream>>>(x, W0, dinv, T0_h, N);
    agg_es<2, true><<<AGB2, 256, 0, stream>>>(row_ptr, perm, (const int4*)T0_h, dinv, b0, T1_h, N);

    // ---- layer 1: AG1 = dinv*sum(T1) fp32 ; T2 = dinv*elu(AG1@W1+b1) fp16
    agg_es<2, false><<<AGB2, 256, 0, stream>>>(row_ptr, perm, (const int4*)T1_h, dinv, nullptr, AG1_f, N);
    gemm_small<16, 32, true, true><<<(N + 7) / 8, 256, 0, stream>>>(AG1_f, W1, b1, dinv, T2_h, N);

    // ---- layer 2: AG2 = dinv*sum(T2) fp32 ; H3 = elu(AG2@W2+b2) fp32
    agg_es<4, false><<<AGB4, 256, 0, stream>>>(row_ptr, perm, (const int4*)T2_h, dinv, nullptr, AG2_f, N);
    gemm_small<32, 32, true, false><<<(N + 7) / 8, 256, 0, stream>>>(AG2_f, W2, b2, nullptr, H3_f, N);

    // ---- head: out = H3@Wm + bm
    gemm_small<32, 16, false, false><<<(N + 15) / 16, 256, 0, stream>>>(H3_f, Wm, bm, nullptr, out, N);
}

// Round 21
// 411.675 us; speedup vs baseline: 1.1754x; 1.0032x over previous
//
#include <hip/hip_runtime.h>
#include <hip/hip_fp16.h>
#include <cstdint>

// ---------------------------------------------------------------------------
// GCN: 3x GCNConv(+ELU) + linear head.
// Norm factorized: norm = dinv[s]*w*dinv[d]. Gather tables store
// t[n] = dinv[n]*f[n] (fp16); agg computes out = dinv[d]*(t[d] + sum w*t[s]).
// perm = (src, w); build: hist(int4) -> scan -> LDS-tile scatter (1024 thr,
// 4 edges/thr, wave-shfl scan) -> bucket_sort (packed 64-bit cnt+deg atomic,
// wave-shfl scan, 4-deep unrolled sweeps).
// Agg: plain-load perm stream + fp16 L2-resident tables + edge-split lanes
// (converged at the measured ~3.4TB/s scattered-gather ceiling).
// ---------------------------------------------------------------------------

union H2I { __half2 h; int i; };
__device__ inline int h2i(__half2 h) { H2I u; u.h = h; return u.i; }

__device__ inline void acc8(float* a, int4 v, float n) {
    H2I u0, u1, u2, u3;
    u0.i = v.x; u1.i = v.y; u2.i = v.z; u3.i = v.w;
    float2 f0 = __half22float2(u0.h);
    float2 f1 = __half22float2(u1.h);
    float2 f2 = __half22float2(u2.h);
    float2 f3 = __half22float2(u3.h);
    a[0] = fmaf(n, f0.x, a[0]); a[1] = fmaf(n, f0.y, a[1]);
    a[2] = fmaf(n, f1.x, a[2]); a[3] = fmaf(n, f1.y, a[3]);
    a[4] = fmaf(n, f2.x, a[4]); a[5] = fmaf(n, f2.y, a[5]);
    a[6] = fmaf(n, f3.x, a[6]); a[7] = fmaf(n, f3.y, a[7]);
}

__device__ inline int4 pack8h(const float* a) {
    int4 r;
    r.x = h2i(__floats2half2_rn(a[0], a[1]));
    r.y = h2i(__floats2half2_rn(a[2], a[3]));
    r.z = h2i(__floats2half2_rn(a[4], a[5]));
    r.w = h2i(__floats2half2_rn(a[6], a[7]));
    return r;
}

// inclusive wave scan (64 lanes)
__device__ inline int wave_iscan(int v, int lane) {
#pragma unroll
    for (int off = 1; off < 64; off <<= 1) {
        int u = __shfl_up(v, off);
        if (lane >= off) v += u;
    }
    return v;
}

// ---- Pass A: per-bucket edge counts. bucket = dst >> 8. int4 loads.
__global__ void __launch_bounds__(256) bucket_hist(const int* __restrict__ dst,
                                                   int* __restrict__ bcnt,
                                                   int E, int nbuck, int chunk) {
    __shared__ int h[512];
    for (int i = threadIdx.x; i < 512; i += 256) h[i] = 0;
    __syncthreads();
    const int4* d4 = (const int4*)dst;
    int q0 = (blockIdx.x * chunk) >> 2;
    int q1 = min(E >> 2, q0 + (chunk >> 2));
    for (int i = q0 + threadIdx.x; i < q1; i += 256) {
        int4 v = d4[i];
        atomicAdd(&h[((unsigned)v.x) >> 8], 1);
        atomicAdd(&h[((unsigned)v.y) >> 8], 1);
        atomicAdd(&h[((unsigned)v.z) >> 8], 1);
        atomicAdd(&h[((unsigned)v.w) >> 8], 1);
    }
    if (blockIdx.x == 0) {  // tail (E % 4)
        for (int e = (E & ~3) + threadIdx.x; e < E; e += 256)
            atomicAdd(&h[((unsigned)dst[e]) >> 8], 1);
    }
    __syncthreads();
    for (int i = threadIdx.x; i < nbuck; i += 256)
        if (h[i]) atomicAdd(&bcnt[i], h[i]);
}

// ---- scan of bucket counts -> boff[nbuck+1], global cursors.
__global__ void __launch_bounds__(512) bucket_scan(const int* __restrict__ bcnt,
                                                   int* __restrict__ boff,
                                                   int* __restrict__ gcur,
                                                   int nbuck) {
    __shared__ int part[512];
    int t = threadIdx.x;
    part[t] = (t < nbuck) ? bcnt[t] : 0;
    __syncthreads();
    for (int off = 1; off < 512; off <<= 1) {
        int v = part[t];
        int a = (t >= off) ? part[t - off] : 0;
        __syncthreads();
        part[t] = v + a;
        __syncthreads();
    }
    if (t < nbuck) {
        int excl = (t > 0) ? part[t - 1] : 0;
        boff[t] = excl;
        gcur[t] = excl;
        if (t == nbuck - 1) boff[nbuck] = part[t];  // == E
    }
}

// ---- Pass C: LDS counting-sort of 4096-edge tiles.
// 1024 thr x 4 edges/thr (halved serial LDS-atomic chains vs 512x8).
// pack: (local_dst(8b) << 24) | src(24b), payload = w
__global__ void __launch_bounds__(1024) bucket_scatter(const int* __restrict__ src,
                                                       const int* __restrict__ dst,
                                                       const float* __restrict__ w,
                                                       int* __restrict__ gcur,
                                                       int2* __restrict__ bedge,
                                                       int E) {
    constexpr int TILE = 4096;
    __shared__ int hc[512];     // histogram, then cursor (local offsets)
    __shared__ int gb[512];
    __shared__ int wsum[8];
    __shared__ int2 sedge[TILE];
    __shared__ unsigned short sbuck[TILE];

    int t = threadIdx.x;
    int c0 = blockIdx.x * TILE;
    int mtile = min(TILE, E - c0);

    if (t < 512) hc[t] = 0;
    __syncthreads();

    int  my_d[4];
    int  my_s[4];
    float my_w[4];
    {
        int e0 = c0 + t * 4;
        if (e0 + 4 <= E) {
            int4 d4 = *(const int4*)(dst + e0);
            int4 s4 = *(const int4*)(src + e0);
            float4 w4 = *(const float4*)(w + e0);
            my_d[0]=d4.x; my_d[1]=d4.y; my_d[2]=d4.z; my_d[3]=d4.w;
            my_s[0]=s4.x; my_s[1]=s4.y; my_s[2]=s4.z; my_s[3]=s4.w;
            my_w[0]=w4.x; my_w[1]=w4.y; my_w[2]=w4.z; my_w[3]=w4.w;
        } else {
#pragma unroll
            for (int j = 0; j < 4; ++j) {
                int e = e0 + j;
                bool ok = e < E;
                my_d[j] = ok ? dst[e] : -1;
                my_s[j] = ok ? src[e] : 0;
                my_w[j] = ok ? w[e] : 0.f;
            }
        }
    }
#pragma unroll
    for (int j = 0; j < 4; ++j)
        if (my_d[j] >= 0) atomicAdd(&hc[((unsigned)my_d[j]) >> 8], 1);
    __syncthreads();

    // wave-level scan of hc[512] (first 8 waves), 2 barriers
    int lane = t & 63;
    int wid = t >> 6;
    int hb = 0, isc = 0;
    if (t < 512) {
        hb = hc[t];
        isc = wave_iscan(hb, lane);
        if (lane == 63) wsum[wid] = isc;
    }
    __syncthreads();
    if (t < 8) {
        int v = wsum[t];
#pragma unroll
        for (int off = 1; off < 8; off <<= 1) {
            int u = __shfl_up(v, off);
            if (t >= off) v += u;
        }
        wsum[t] = v;
    }
    __syncthreads();
    if (t < 512) {
        int excl = (wid ? wsum[wid - 1] : 0) + isc - hb;
        hc[t] = excl;                                   // cursor = local offset
        gb[t] = hb ? (atomicAdd(&gcur[t], hb) - excl) : 0;
    }
    __syncthreads();

#pragma unroll
    for (int j = 0; j < 4; ++j) {
        int d = my_d[j];
        if (d < 0) continue;
        unsigned ud = (unsigned)d;
        int b = ud >> 8;
        int p = atomicAdd(&hc[b], 1);
        sedge[p] = make_int2((int)(((ud & 255u) << 24) | (unsigned)my_s[j]),
                             __float_as_int(my_w[j]));
        sbuck[p] = (unsigned short)b;
    }
    __syncthreads();

    for (int i = t; i < mtile; i += 1024) {
        int b = sbuck[i];
        bedge[gb[b] + i] = sedge[i];
    }
}

// ---- Pass D (fused, 1024 thr): sweep 1 uses ONE packed 64-bit LDS atomic
// per edge (count in bits 42+, w fixed-point 2^-24 in low bits); wave-shfl
// scan; sweep 2 scatters perm=(src,w) with 4-deep unroll.
__global__ void __launch_bounds__(1024) bucket_sort(const int* __restrict__ boff,
                                                    const int2* __restrict__ bedge,
                                                    int* __restrict__ row_ptr,
                                                    float* __restrict__ dinv,
                                                    int2* __restrict__ perm,
                                                    int N, int E) {
    __shared__ unsigned long long pack[256];
    __shared__ int cur[256];
    __shared__ int wsum[4];
    int b = blockIdx.x;
    int base = boff[b];
    int m = boff[b + 1] - base;
    int t = threadIdx.x;
    if (t < 256) pack[t] = 0ull;
    __syncthreads();
    const float FIX = 16777216.0f;  // 2^24
    int i = t;
    for (; i + 3072 < m; i += 4096) {
        int2 e0 = bedge[base + i];
        int2 e1 = bedge[base + i + 1024];
        int2 e2 = bedge[base + i + 2048];
        int2 e3 = bedge[base + i + 3072];
        atomicAdd(&pack[((unsigned)e0.x) >> 24],
                  (1ull << 42) | (unsigned long long)(unsigned)(__int_as_float(e0.y) * FIX));
        atomicAdd(&pack[((unsigned)e1.x) >> 24],
                  (1ull << 42) | (unsigned long long)(unsigned)(__int_as_float(e1.y) * FIX));
        atomicAdd(&pack[((unsigned)e2.x) >> 24],
                  (1ull << 42) | (unsigned long long)(unsigned)(__int_as_float(e2.y) * FIX));
        atomicAdd(&pack[((unsigned)e3.x) >> 24],
                  (1ull << 42) | (unsigned long long)(unsigned)(__int_as_float(e3.y) * FIX));
    }
    for (; i < m; i += 1024) {
        int2 e = bedge[base + i];
        atomicAdd(&pack[((unsigned)e.x) >> 24],
                  (1ull << 42) | (unsigned long long)(unsigned)(__int_as_float(e.y) * FIX));
    }
    __syncthreads();
    // wave-level scan of counts (first 256 threads = 4 waves), 2 barriers
    int cnt_t = 0, isc = 0;
    int lane = t & 63;
    int wid = t >> 6;
    if (t < 256) {
        cnt_t = (int)(pack[t] >> 42);
        isc = wave_iscan(cnt_t, lane);
        if (lane == 63) wsum[wid] = isc;
    }
    __syncthreads();
    if (t < 4) {
        int v = wsum[t];
#pragma unroll
        for (int off = 1; off < 4; off <<= 1) {
            int u = __shfl_up(v, off);
            if (t >= off) v += u;
        }
        wsum[t] = v;
    }
    __syncthreads();
    if (t < 256) {
        int excl = (wid ? wsum[wid - 1] : 0) + isc - cnt_t;
        cur[t] = excl;
        int node = b * 256 + t;
        if (node < N) {
            row_ptr[node] = base + excl;
            float deg = (float)(pack[t] & ((1ull << 42) - 1)) * 5.9604644775390625e-08f;
            dinv[node] = rsqrtf(deg + 1.0f);
        }
    }
    if (b == 0 && t == 0) row_ptr[N] = E;
    __syncthreads();
    i = t;
    for (; i + 3072 < m; i += 4096) {
        int2 e0 = bedge[base + i];
        int2 e1 = bedge[base + i + 1024];
        int2 e2 = bedge[base + i + 2048];
        int2 e3 = bedge[base + i + 3072];
        unsigned x0 = (unsigned)e0.x, x1 = (unsigned)e1.x;
        unsigned x2 = (unsigned)e2.x, x3 = (unsigned)e3.x;
        int p0 = base + atomicAdd(&cur[x0 >> 24], 1);
        int p1 = base + atomicAdd(&cur[x1 >> 24], 1);
        int p2 = base + atomicAdd(&cur[x2 >> 24], 1);
        int p3 = base + atomicAdd(&cur[x3 >> 24], 1);
        perm[p0] = make_int2((int)(x0 & 0xFFFFFFu), e0.y);
        perm[p1] = make_int2((int)(x1 & 0xFFFFFFu), e1.y);
        perm[p2] = make_int2((int)(x2 & 0xFFFFFFu), e2.y);
        perm[p3] = make_int2((int)(x3 & 0xFFFFFFu), e3.y);
    }
    for (; i < m; i += 1024) {
        int2 e = bedge[base + i];
        unsigned ux = (unsigned)e.x;
        int pos = base + atomicAdd(&cur[ux >> 24], 1);
        perm[pos] = make_int2((int)(ux & 0xFFFFFFu), e.y);
    }
}

// ---- x[N,256] @ W[256,16], prescaled by dinv[r] -> fp16 [N,16].
// LDS-staged: 16 rows of x (coalesced plain loads) + transposed W.
__global__ void __launch_bounds__(256) gemm_x16(const float* __restrict__ x,
                                                const float* __restrict__ W,
                                                const float* __restrict__ dinv,
                                                __half* __restrict__ xwh, int N) {
    __shared__ float Is[16][260];
    __shared__ float Wt[16][260];
    int t = threadIdx.x;
    int r0 = blockIdx.x * 16;
    for (int i = t; i < 4096; i += 256) {
        int k = i >> 4, c = i & 15;
        Wt[c][k] = W[i];
    }
    const float4* xb = (const float4*)(x + (size_t)r0 * 256);
    for (int i = t; i < 1024; i += 256) {
        int row = i >> 6, k4 = i & 63;
        float4 v;
        if (r0 + row < N) v = xb[(size_t)row * 64 + k4];
        else v = make_float4(0.f, 0.f, 0.f, 0.f);
        *(float4*)&Is[row][k4 * 4] = v;
    }
    __syncthreads();
    int c = t & 15;
    int rl = t >> 4;
    int r = r0 + rl;
    if (r >= N) return;
    float acc = 0.f;
#pragma unroll 16
    for (int k4 = 0; k4 < 64; ++k4) {
        float4 iv = *(const float4*)&Is[rl][k4 * 4];
        float4 wv = *(const float4*)&Wt[c][k4 * 4];
        acc += iv.x * wv.x + iv.y * wv.y + iv.z * wv.z + iv.w * wv.w;
    }
    xwh[(size_t)r * 16 + c] = __float2half_rn(acc * dinv[r]);
}

// in[N,K] @ W[K,F] + bias -> out[N,F]. OUT_ELU: apply ELU.
// HALF_ROW: write fp16 row-major [N][F] prescaled by dinv[r]; else fp32.
template <int K, int F, bool OUT_ELU, bool HALF_ROW>
__global__ void __launch_bounds__(256) gemm_small(const float* __restrict__ in,
                                                  const float* __restrict__ W,
                                                  const float* __restrict__ bias,
                                                  const float* __restrict__ dinv,
                                                  void* __restrict__ outv, int N) {
    constexpr int ROWS = 256 / F;
    __shared__ float Ws[K * F];
    __shared__ float Is[ROWS * K];
    for (int i = threadIdx.x; i < K * F; i += 256) Ws[i] = W[i];
    int r0 = blockIdx.x * ROWS;
    for (int i = threadIdx.x; i < ROWS * K; i += 256)
        Is[i] = in[(size_t)r0 * K + i];
    __syncthreads();
    int c = threadIdx.x % F;
    int rl = threadIdx.x / F;
    int r = r0 + rl;
    float acc = bias[c];
#pragma unroll
    for (int k = 0; k < K; ++k) acc += Is[rl * K + k] * Ws[k * F + c];
    if (OUT_ELU) acc = acc > 0.f ? acc : expm1f(acc);
    if (HALF_ROW) {
        ((__half*)outv)[(size_t)r * F + c] = __float2half_rn(acc * dinv[r]);
    } else {
        ((float*)outv)[(size_t)r * F + c] = acc;
    }
}

// ---- fp16 prescaled-table gather-aggregate with edge-split lanes.
// Table: t[n] = dinv[n]*f[n], fp16 row-major [N][8*FH] (int4 = node*FH + q).
// Lanes/node = FH*2: q = feature chunk, e = edge half; shfl_xor(FH) merges.
// Math: sum = t[node] + sum_e w_e * t[src_e]; out = dinv[node]*sum [+b, ELU].
template <int FH, bool HALF_OUT>
__global__ void __launch_bounds__(256) agg_es(const int* __restrict__ row_ptr,
                                              const int2* __restrict__ perm,
                                              const int4* __restrict__ tab,
                                              const float* __restrict__ dinv,
                                              const float* __restrict__ bias,
                                              void* __restrict__ outv, int N) {
    constexpr int LPN = FH * 2;
    constexpr int NPB = 256 / LPN;
    int node = blockIdx.x * NPB + threadIdx.x / LPN;
    int sub = threadIdx.x % LPN;
    int q = sub % FH;
    int e = sub / FH;
    if (node >= N) return;
    float a0[8], a1[8], a2[8], a3[8];
#pragma unroll
    for (int i = 0; i < 8; ++i) { a0[i] = 0.f; a1[i] = 0.f; a2[i] = 0.f; a3[i] = 0.f; }
    if (e == 0) acc8(a0, tab[(size_t)node * FH + q], 1.0f);   // self-loop (w=1)
    int beg = row_ptr[node];
    int end = row_ptr[node + 1];
    int half = (end - beg) >> 1;
    int j = beg + e * half;
    int je = e ? end : (beg + half);
    for (; j + 7 < je; j += 8) {
        int2 p0 = perm[j];
        int2 p1 = perm[j + 1];
        int2 p2 = perm[j + 2];
        int2 p3 = perm[j + 3];
        int2 p4 = perm[j + 4];
        int2 p5 = perm[j + 5];
        int2 p6 = perm[j + 6];
        int2 p7 = perm[j + 7];
        int4 v0 = tab[(size_t)p0.x * FH + q];
        int4 v1 = tab[(size_t)p1.x * FH + q];
        int4 v2 = tab[(size_t)p2.x * FH + q];
        int4 v3 = tab[(size_t)p3.x * FH + q];
        int4 v4 = tab[(size_t)p4.x * FH + q];
        int4 v5 = tab[(size_t)p5.x * FH + q];
        int4 v6 = tab[(size_t)p6.x * FH + q];
        int4 v7 = tab[(size_t)p7.x * FH + q];
        acc8(a0, v0, __int_as_float(p0.y));
        acc8(a1, v1, __int_as_float(p1.y));
        acc8(a2, v2, __int_as_float(p2.y));
        acc8(a3, v3, __int_as_float(p3.y));
        acc8(a0, v4, __int_as_float(p4.y));
        acc8(a1, v5, __int_as_float(p5.y));
        acc8(a2, v6, __int_as_float(p6.y));
        acc8(a3, v7, __int_as_float(p7.y));
    }
    for (; j + 3 < je; j += 4) {
        int2 p0 = perm[j];
        int2 p1 = perm[j + 1];
        int2 p2 = perm[j + 2];
        int2 p3 = perm[j + 3];
        int4 v0 = tab[(size_t)p0.x * FH + q];
        int4 v1 = tab[(size_t)p1.x * FH + q];
        int4 v2 = tab[(size_t)p2.x * FH + q];
        int4 v3 = tab[(size_t)p3.x * FH + q];
        acc8(a0, v0, __int_as_float(p0.y));
        acc8(a1, v1, __int_as_float(p1.y));
        acc8(a2, v2, __int_as_float(p2.y));
        acc8(a3, v3, __int_as_float(p3.y));
    }
    for (; j < je; ++j) {
        int2 p0 = perm[j];
        acc8(a0, tab[(size_t)p0.x * FH + q], __int_as_float(p0.y));
    }
    float r[8];
#pragma unroll
    for (int i = 0; i < 8; ++i) {
        r[i] = (a0[i] + a1[i]) + (a2[i] + a3[i]);
        r[i] += __shfl_xor(r[i], FH);     // merge edge halves
    }
    if (e) return;
    float dv = dinv[node];
    if (HALF_OUT) {
#pragma unroll
        for (int i = 0; i < 8; ++i) {
            float v = r[i] * dv + bias[q * 8 + i];
            v = v > 0.f ? v : expm1f(v);
            r[i] = v * dv;                 // prescale next table
        }
        ((int4*)outv)[(size_t)node * FH + q] = pack8h(r);
    } else {
        float4* o4 = (float4*)outv;
        float4 lo = {r[0] * dv, r[1] * dv, r[2] * dv, r[3] * dv};
        float4 hi = {r[4] * dv, r[5] * dv, r[6] * dv, r[7] * dv};
        size_t base = ((size_t)node * FH + q) * 2;
        o4[base] = lo;
        o4[base + 1] = hi;
    }
}

extern "C" void kernel_launch(void* const* d_in, const int* in_sizes, int n_in,
                              void* d_out, int out_size, void* d_ws, size_t ws_size,
                              hipStream_t stream) {
    const float* x  = (const float*)d_in[0];
    const int*   ei = (const int*)d_in[1];
    const float* w  = (const float*)d_in[2];
    const float* W0 = (const float*)d_in[3];
    const float* b0 = (const float*)d_in[4];
    const float* W1 = (const float*)d_in[5];
    const float* b1 = (const float*)d_in[6];
    const float* W2 = (const float*)d_in[7];
    const float* b2 = (const float*)d_in[8];
    const float* Wm = (const float*)d_in[9];
    const float* bm = (const float*)d_in[10];
    float* out = (float*)d_out;

    const int N = in_sizes[0] / 256;
    const int E = in_sizes[2];
    const int* src = ei;
    const int* dst = ei + E;
    const int nbuck = (N + 255) >> 8;      // 256-node buckets (<=512)

    char* ws = (char*)d_ws;
    size_t off = 0;
    auto alloc = [&](size_t bytes) {
        void* p = ws + off;
        off = (off + bytes + 255) & ~(size_t)255;
        return p;
    };
    float* dinv    = (float*)alloc((size_t)N * 4);
    int*   row_ptr = (int*)alloc(((size_t)N + 1) * 4);
    int*   bcnt    = (int*)alloc(520 * 4);
    int*   boff    = (int*)alloc(520 * 4);
    int*   gcur    = (int*)alloc(520 * 4);
    // bedge region (E*8 bytes), aliased by feature buffers after CSR build:
    char*  regE    = (char*)alloc((size_t)E * 8);
    int2*  perm    = (int2*)alloc((size_t)E * 8);

    int2*  bedge = (int2*)regE;
    size_t eo = 0;
    auto sub = [&](size_t bytes) {
        char* p = regE + eo;
        eo = (eo + bytes + 255) & ~(size_t)255;
        return p;
    };
    __half* T0_h  = (__half*)sub((size_t)N * 16 * 2);   // 3.2MB  dinv*xw
    __half* T1_h  = (__half*)sub((size_t)N * 16 * 2);   // 3.2MB  dinv*h1
    __half* T2_h  = (__half*)sub((size_t)N * 32 * 2);   // 6.4MB  dinv*h2 [N][32]
    float*  AG1_f = (float*)sub((size_t)N * 16 * 4);    // 6.4MB
    float*  AG2_f = (float*)sub((size_t)N * 32 * 4);    // 12.8MB
    float*  H3_f  = (float*)sub((size_t)N * 32 * 4);    // 12.8MB (total ~44.8MB <= E*8)

    hipMemsetAsync(bcnt, 0, 520 * 4, stream);

    const int CH = 8192;
    const int sblk = (E + CH - 1) / CH;

    // ---- build CSR (layer-invariant): perm = (src, w)
    bucket_hist<<<sblk, 256, 0, stream>>>(dst, bcnt, E, nbuck, CH);
    bucket_scan<<<1, 512, 0, stream>>>(bcnt, boff, gcur, nbuck);
    bucket_scatter<<<(E + 4095) / 4096, 1024, 0, stream>>>(src, dst, w, gcur, bedge, E);
    bucket_sort<<<nbuck, 1024, 0, stream>>>(boff, bedge, row_ptr, dinv, perm, N, E);
    // bedge dead from here; regE reused for feature buffers.

    const int AGB2 = (N + 63) / 64;     // FH=2: 4 lanes/node
    const int AGB4 = (N + 31) / 32;     // FH=4: 8 lanes/node

    // ---- layer 0: T0 = dinv*(x@W0) fp16 ; T1 = dinv*elu(dinv*sum + b0) fp16
    gemm_x16<<<(N + 15) / 16, 256, 0, stream>>>(x, W0, dinv, T0_h, N);
    agg_es<2, true><<<AGB2, 256, 0, stream>>>(row_ptr, perm, (const int4*)T0_h, dinv, b0, T1_h, N);

    // ---- layer 1: AG1 = dinv*sum(T1) fp32 ; T2 = dinv*elu(AG1@W1+b1) fp16
    agg_es<2, false><<<AGB2, 256, 0, stream>>>(row_ptr, perm, (const int4*)T1_h, dinv, nullptr, AG1_f, N);
    gemm_small<16, 32, true, true><<<(N + 7) / 8, 256, 0, stream>>>(AG1_f, W1, b1, dinv, T2_h, N);

    // ---- layer 2: AG2 = dinv*sum(T2) fp32 ; H3 = elu(AG2@W2+b2) fp32
    agg_es<4, false><<<AGB4, 256, 0, stream>>>(row_ptr, perm, (const int4*)T2_h, dinv, nullptr, AG2_f, N);
    gemm_small<32, 32, true, false><<<(N + 7) / 8, 256, 0, stream>>>(AG2_f, W2, b2, nullptr, H3_f, N);

    // ---- head: out = H3@Wm + bm
    gemm_small<32, 16, false, false><<<(N + 15) / 16, 256, 0, stream>>>(H3_f, Wm, bm, nullptr, out, N);
}